// Round 4
// baseline (828.561 us; speedup 1.0000x reference)
//
#include <hip/hip_runtime.h>
#include <cstdint>

typedef unsigned short u16;
typedef __attribute__((ext_vector_type(8))) short short8;   // 8 x bf16 (4 VGPR)
typedef __attribute__((ext_vector_type(4))) short short4v;  // 4 x bf16
typedef __attribute__((ext_vector_type(4))) float floatx4;  // MFMA acc / float4

#define DEV __device__ __forceinline__

DEV float bf2f(u16 u) { union { uint32_t i; float f; } w; w.i = ((uint32_t)u) << 16; return w.f; }
DEV u16 f2bf(float f) {
  union { float f; uint32_t i; } w; w.f = f;
  uint32_t x = w.i;
  return (u16)((x + 0x7fffu + ((x >> 16) & 1u)) >> 16);  // RNE
}

// fast exact-gelu: A&S 7.1.26 erf approx, |err|<=1.5e-7, branchless
DEV float fast_gelu(float x) {
  const float y = x * 0.70710678118f;
  const float ay = fabsf(y);
  const float t = 1.f / (1.f + 0.3275911f * ay);
  const float poly = t * (0.254829592f + t * (-0.284496736f +
                     t * (1.421413741f + t * (-1.453152027f + t * 1.061405429f))));
  const float er = 1.f - poly * __expf(-y * y);
  const float erf_y = __builtin_copysignf(er, y);
  return 0.5f * x * (1.f + erf_y);
}

// async global->LDS, 16B per lane. LDS dest must be wave-uniform base; HW adds lane*16.
DEV void async_copy16(const u16* g, u16* l) {
  __builtin_amdgcn_global_load_lds(
      (const __attribute__((address_space(1))) void*)(uintptr_t)g,
      (__attribute__((address_space(3))) void*)(uint32_t)(uintptr_t)l,
      16, 0, 0);
}

// ---------------- fused f32 -> bf16 weight convert (all 10 weights) ----------------
// dst layout (contiguous): rq,rk,rv,ro,cq,ck,cv,co (589824 each), f1,f2 (2359296 each)
struct CvtArgs {
  const float* src[10];
  float scale[10];
};
__global__ __launch_bounds__(256) void cvt_all(CvtArgs a, u16* __restrict__ dst) {
  const size_t e = ((size_t)blockIdx.x * 256 + threadIdx.x) * 4;  // 9437184 total elems
  if (e >= 9437184) return;
  int reg;
  size_t base;
  if (e < 4718592) { reg = (int)(e / 589824); base = (size_t)reg * 589824; }
  else if (e < 7077888) { reg = 8; base = 4718592; }
  else { reg = 9; base = 7077888; }
  const float sc = a.scale[reg];
  floatx4 f = *(const floatx4*)(a.src[reg] + (e - base));
  short4v o;
#pragma unroll
  for (int j = 0; j < 4; ++j) o[j] = (short)f2bf(f[j] * sc);
  *(short4v*)(dst + e) = o;
}

// pack q/k/v biases into one [2304] f32 buffer per stage, q part pre-scaled
__global__ __launch_bounds__(256) void bias_pack(const float* __restrict__ qb,
                                                 const float* __restrict__ kb,
                                                 const float* __restrict__ vb,
                                                 float sq, float* __restrict__ out) {
  const int i = blockIdx.x * 256 + threadIdx.x;
  if (i >= 2304) return;
  const int buf = i / 768, c = i - buf * 768;
  out[i] = buf == 0 ? qb[c] * sq : (buf == 1 ? kb[c] : vb[c]);
}

// ---------------- LayerNorm: one wave per row of 768, bf16 out ----------------
template<bool INF32>
__global__ __launch_bounds__(256) void ln_kernel(const void* __restrict__ in,
                                                 const float* __restrict__ w,
                                                 const float* __restrict__ b,
                                                 u16* __restrict__ out) {
  const int wid = threadIdx.x >> 6, lane = threadIdx.x & 63;
  const int row = blockIdx.x * 4 + wid;  // 16384 rows
  const size_t base = (size_t)row * 768;
  float v[12];
#pragma unroll
  for (int p = 0; p < 3; ++p) {
    const int e = p * 256 + lane * 4;
    if constexpr (INF32) {
      floatx4 f = *(const floatx4*)((const float*)in + base + e);
#pragma unroll
      for (int j = 0; j < 4; ++j) v[p * 4 + j] = f[j];
    } else {
      short4v u = *(const short4v*)((const u16*)in + base + e);
#pragma unroll
      for (int j = 0; j < 4; ++j) v[p * 4 + j] = bf2f((u16)u[j]);
    }
  }
  float s = 0.f, sq = 0.f;
#pragma unroll
  for (int i = 0; i < 12; ++i) { s += v[i]; sq += v[i] * v[i]; }
#pragma unroll
  for (int m = 1; m < 64; m <<= 1) { s += __shfl_xor(s, m); sq += __shfl_xor(sq, m); }
  const float mean = s * (1.f / 768.f);
  const float var = sq * (1.f / 768.f) - mean * mean;
  const float rstd = rsqrtf(var + 1e-5f);
#pragma unroll
  for (int p = 0; p < 3; ++p) {
    const int e = p * 256 + lane * 4;
    floatx4 wv = *(const floatx4*)(w + e);
    floatx4 bv = *(const floatx4*)(b + e);
    short4v o;
#pragma unroll
    for (int j = 0; j < 4; ++j) {
      float y = (v[p * 4 + j] - mean) * rstd * wv[j] + bv[j];
      o[j] = (short)f2bf(y);
    }
    *(short4v*)(out + base + e) = o;
  }
}

// ---------------- GEMM: C[M,N] = A[M,K] * B[N,K]^T (+epilogue) ----------------
// 128x128 tile, BK=64 (2 sequential k-halves), 4 waves (2x2), mfma 16x16x32 bf16.
// AMODE: 0 = normal strides lda/ldb
//        1 = row-attn logits addressing: elem(row,kk) = base + z*96 + (kk/96)*196608 + row*768 + (kk%96)
//        2 = split-K row-attn logits: z = h*16+s, head h, K-window [s*384, s*384+384)
// EPI: 1 f32=acc | 2 bf16=gelu(acc+bz) | 3 f32=resf32+acc+bz | 4 bf16=resf32+acc+bz
//      5 f32=resbf16+acc+bz | 6 bf16=resbf16+acc+bz
//      7 bf16 scatter (row-attn PV): n=(r*96+d) -> out[(r*256+m)*768 + z*96 + d]
//      8 bf16 merged-QKV split write: buf=n/768 -> out + buf*12582912 + m*768 + (n%768)
template<int AMODE, int EPI>
__global__ __launch_bounds__(256) void gemm_bt(
    const u16* __restrict__ A, const u16* __restrict__ B,
    const float* __restrict__ bias, const void* __restrict__ res,
    void* __restrict__ out, int K, int lda, int ldb,
    long long aBatch, long long bBatch, long long outBatch, int ldc, float scale) {
  __shared__ u16 lA[128 * 64];
  __shared__ u16 lB[128 * 64];
  const int t = threadIdx.x;
  const int z = blockIdx.z;
  const int m0 = blockIdx.x * 128, n0 = blockIdx.y * 128;
  const u16* Ab;
  const u16* Bb;
  int koff = 0;
  if constexpr (AMODE == 0) { Ab = A + (size_t)z * aBatch; Bb = B + (size_t)z * bBatch; }
  else if constexpr (AMODE == 1) { Ab = A + z * 96; Bb = B + z * 96; }
  else { const int h = z >> 4; Ab = A + h * 96; Bb = B + h * 96; koff = (z & 15) * 384; }

  const int srow = t >> 3;          // 0..31 (staging row within a 32-row pass)
  const int scol = (t & 7) << 3;    // 0,8,...,56
  const int wid = t >> 6, lane = t & 63;
  const int wr = wid >> 1, wc = wid & 1;
  const int lrow = lane & 15, lhi = lane >> 4;

  floatx4 acc[4][4];
#pragma unroll
  for (int i = 0; i < 4; ++i)
#pragma unroll
    for (int j = 0; j < 4; ++j) acc[i][j] = (floatx4){0.f, 0.f, 0.f, 0.f};

  for (int k0 = 0; k0 < K; k0 += 64) {
#pragma unroll
    for (int p = 0; p < 4; ++p) {
      const int row = p * 32 + srow;
      const int kk = koff + k0 + scol;
      const u16 *ga, *gb;
      if constexpr (AMODE == 0) {
        ga = Ab + (size_t)(m0 + row) * lda + kk;
        gb = Bb + (size_t)(n0 + row) * ldb + kk;
      } else {
        const int r = kk / 96, d = kk - r * 96;  // 8|96 so a lane's 8-chunk never crosses r
        ga = Ab + (size_t)r * 196608 + (size_t)(m0 + row) * 768 + d;
        gb = Bb + (size_t)r * 196608 + (size_t)(n0 + row) * 768 + d;
      }
      async_copy16(ga, lA + p * 2048 + wid * 512);
      async_copy16(gb, lB + p * 2048 + wid * 512);
    }
    asm volatile("s_waitcnt vmcnt(0)" ::: "memory");
    __syncthreads();

#pragma unroll
    for (int kh = 0; kh < 2; ++kh) {
      short8 af[4], bfr[4];
#pragma unroll
      for (int mi = 0; mi < 4; ++mi)
        af[mi] = *(const short8*)&lA[(wr * 64 + mi * 16 + lrow) * 64 + kh * 32 + lhi * 8];
#pragma unroll
      for (int ni = 0; ni < 4; ++ni)
        bfr[ni] = *(const short8*)&lB[(wc * 64 + ni * 16 + lrow) * 64 + kh * 32 + lhi * 8];
#pragma unroll
      for (int mi = 0; mi < 4; ++mi)
#pragma unroll
        for (int ni = 0; ni < 4; ++ni)
          acc[mi][ni] = __builtin_amdgcn_mfma_f32_16x16x32_bf16(af[mi], bfr[ni], acc[mi][ni], 0, 0, 0);
    }
    __syncthreads();
  }

  const int mbase = m0 + wr * 64;
  const int nbase = n0 + wc * 64;
#pragma unroll
  for (int mi = 0; mi < 4; ++mi) {
#pragma unroll
    for (int ni = 0; ni < 4; ++ni) {
      const int n = nbase + ni * 16 + lrow;
      float bz = 0.f;
      if constexpr (EPI != 1 && EPI != 7) { if (bias) bz = bias[n]; }
#pragma unroll
      for (int r4 = 0; r4 < 4; ++r4) {
        const int m = mbase + mi * 16 + lhi * 4 + r4;
        const float val = acc[mi][ni][r4];
        if constexpr (EPI == 1) {
          ((float*)out)[(size_t)z * outBatch + (size_t)m * ldc + n] = val;
        } else if constexpr (EPI == 2) {
          ((u16*)out)[(size_t)m * ldc + n] = f2bf(fast_gelu(val + bz));
        } else if constexpr (EPI == 3) {
          const float r = ((const float*)res)[(size_t)m * ldc + n];
          ((float*)out)[(size_t)m * ldc + n] = r + val + bz;
        } else if constexpr (EPI == 4) {
          const float r = ((const float*)res)[(size_t)m * ldc + n];
          ((u16*)out)[(size_t)m * ldc + n] = f2bf(r + val + bz);
        } else if constexpr (EPI == 5) {
          const float r = bf2f(((const u16*)res)[(size_t)m * ldc + n]);
          ((float*)out)[(size_t)m * ldc + n] = r + val + bz;
        } else if constexpr (EPI == 6) {
          const float r = bf2f(((const u16*)res)[(size_t)m * ldc + n]);
          ((u16*)out)[(size_t)m * ldc + n] = f2bf(r + val + bz);
        } else if constexpr (EPI == 7) {
          const int rr = n / 96, d = n - rr * 96;
          ((u16*)out)[((size_t)(rr * 256 + m)) * 768 + (size_t)z * 96 + d] = f2bf(val);
        } else if constexpr (EPI == 8) {
          const int buf = n / 768, col = n - buf * 768;
          ((u16*)out)[(size_t)buf * 12582912 + (size_t)m * 768 + col] = f2bf(val + bz);
        }
      }
    }
  }
}

// ---------------- row softmax fused with split-K reduce ----------------
// part[(h*16+s)*65536 + i*256 + j]; row = h*256+i; 2048 rows, one wave per row.
__global__ __launch_bounds__(256) void softmax_row(const float* __restrict__ part,
                                                   float* __restrict__ probs_f,
                                                   u16* __restrict__ probs_b) {
  const int wid = threadIdx.x >> 6, lane = threadIdx.x & 63;
  const int row = blockIdx.x * 4 + wid;
  const int h = row >> 8, i = row & 255;
  const size_t base = (size_t)h * 16 * 65536 + (size_t)i * 256 + lane * 4;
  floatx4 v = (floatx4){0.f, 0.f, 0.f, 0.f};
#pragma unroll
  for (int s16 = 0; s16 < 16; ++s16) {
    floatx4 p = *(const floatx4*)(part + base + (size_t)s16 * 65536);
#pragma unroll
    for (int j = 0; j < 4; ++j) v[j] += p[j];
  }
  float mx = fmaxf(fmaxf(v[0], v[1]), fmaxf(v[2], v[3]));
#pragma unroll
  for (int m = 1; m < 64; m <<= 1) mx = fmaxf(mx, __shfl_xor(mx, m));
  float e[4], s = 0.f;
#pragma unroll
  for (int j = 0; j < 4; ++j) { e[j] = __expf(v[j] - mx); s += e[j]; }
#pragma unroll
  for (int m = 1; m < 64; m <<= 1) s += __shfl_xor(s, m);
  const float inv = 1.f / s;
  floatx4 of;
  short4v ob;
#pragma unroll
  for (int j = 0; j < 4; ++j) {
    const float p = e[j] * inv;
    of[j] = p;
    ob[j] = (short)f2bf(p);
  }
  *(floatx4*)(probs_f + (size_t)row * 256 + lane * 4) = of;
  *(short4v*)(probs_b + (size_t)row * 256 + lane * 4) = ob;
}

// ---------------- pack V^T for row-attn PV: vt[h][(r*96+d)][j] = v[(r*256+j)*768+h*96+d]
__global__ __launch_bounds__(256) void pack_vt(const u16* __restrict__ v, u16* __restrict__ vt) {
  __shared__ u16 S[64][104];  // [j][d], padded
  const int jb = blockIdx.x, r = blockIdx.y, h = blockIdx.z;
  const int t = threadIdx.x;
#pragma unroll
  for (int p = 0; p < 3; ++p) {
    const int cid = t + p * 256;
    const int j = cid / 12, ch = cid - j * 12;
    short8 x = *(const short8*)&v[((size_t)(r * 256 + jb * 64 + j)) * 768 + h * 96 + ch * 8];
    *(short8*)&S[j][ch * 8] = x;
  }
  __syncthreads();
#pragma unroll
  for (int p = 0; p < 3; ++p) {
    const int cid = t + p * 256;
    const int d = cid / 8, cj = cid - d * 8;
    u16 tmp[8];
#pragma unroll
    for (int m = 0; m < 8; ++m) tmp[m] = S[cj * 8 + m][d];
    *(short8*)&vt[((size_t)(h * 6144 + r * 96 + d)) * 256 + jb * 64 + cj * 8] = *(short8*)tmp;
  }
}

// ---------------- fused column attention: one block per (c, h) ----------------
__global__ __launch_bounds__(256) void col_attn(const u16* __restrict__ q,
                                                const u16* __restrict__ k,
                                                const u16* __restrict__ v,
                                                float* __restrict__ probs,
                                                u16* __restrict__ ctx) {
  __shared__ u16 qs[64][104];
  __shared__ u16 ks[64][104];
  __shared__ u16 vt[96][72];
  __shared__ u16 ps[64][72];
  const int c = blockIdx.x, h = blockIdx.y;
  const int t = threadIdx.x;
#pragma unroll
  for (int p = 0; p < 3; ++p) {
    const int cid = t + p * 256;
    const int i = cid / 12, ch = cid - i * 12;
    const size_t g = ((size_t)(i * 256 + c)) * 768 + h * 96 + ch * 8;
    short8 qv = *(const short8*)(q + g);
    short8 kv = *(const short8*)(k + g);
    short8 vv = *(const short8*)(v + g);
    *(short8*)&qs[i][ch * 8] = qv;
    *(short8*)&ks[i][ch * 8] = kv;
#pragma unroll
    for (int m = 0; m < 8; ++m) vt[ch * 8 + m][i] = (u16)vv[m];
  }
  __syncthreads();
  const int lane = t & 63, wid = t >> 6;
  const int lrow = lane & 15, lhi = lane >> 4;

  floatx4 s[4];
#pragma unroll
  for (int nj = 0; nj < 4; ++nj) s[nj] = (floatx4){0.f, 0.f, 0.f, 0.f};
#pragma unroll
  for (int kk = 0; kk < 3; ++kk) {
    short8 a = *(const short8*)&qs[wid * 16 + lrow][kk * 32 + lhi * 8];
#pragma unroll
    for (int nj = 0; nj < 4; ++nj) {
      short8 bb = *(const short8*)&ks[nj * 16 + lrow][kk * 32 + lhi * 8];
      s[nj] = __builtin_amdgcn_mfma_f32_16x16x32_bf16(a, bb, s[nj], 0, 0, 0);
    }
  }
  const size_t pb = ((size_t)(h * 256 + c)) * 4096;
#pragma unroll
  for (int r4 = 0; r4 < 4; ++r4) {
    float mx = fmaxf(fmaxf(s[0][r4], s[1][r4]), fmaxf(s[2][r4], s[3][r4]));
    mx = fmaxf(mx, __shfl_xor(mx, 1));
    mx = fmaxf(mx, __shfl_xor(mx, 2));
    mx = fmaxf(mx, __shfl_xor(mx, 4));
    mx = fmaxf(mx, __shfl_xor(mx, 8));
    float e[4], sum = 0.f;
#pragma unroll
    for (int nj = 0; nj < 4; ++nj) { e[nj] = __expf(s[nj][r4] - mx); sum += e[nj]; }
    sum += __shfl_xor(sum, 1);
    sum += __shfl_xor(sum, 2);
    sum += __shfl_xor(sum, 4);
    sum += __shfl_xor(sum, 8);
    const float inv = 1.f / sum;
    const int i = wid * 16 + lhi * 4 + r4;
#pragma unroll
    for (int nj = 0; nj < 4; ++nj) {
      const float pv = e[nj] * inv;
      const int j = nj * 16 + lrow;
      probs[pb + (size_t)i * 64 + j] = pv;
      ps[i][j] = f2bf(pv);
    }
  }
  __syncthreads();
  floatx4 o[6];
#pragma unroll
  for (int df = 0; df < 6; ++df) o[df] = (floatx4){0.f, 0.f, 0.f, 0.f};
#pragma unroll
  for (int k2 = 0; k2 < 2; ++k2) {
    short8 a = *(const short8*)&ps[wid * 16 + lrow][k2 * 32 + lhi * 8];
#pragma unroll
    for (int df = 0; df < 6; ++df) {
      short8 bb = *(const short8*)&vt[df * 16 + lrow][k2 * 32 + lhi * 8];
      o[df] = __builtin_amdgcn_mfma_f32_16x16x32_bf16(a, bb, o[df], 0, 0, 0);
    }
  }
#pragma unroll
  for (int df = 0; df < 6; ++df)
#pragma unroll
    for (int r4 = 0; r4 < 4; ++r4) {
      const int i = wid * 16 + lhi * 4 + r4;
      const int d = df * 16 + lrow;
      ctx[((size_t)(i * 256 + c)) * 768 + h * 96 + d] = f2bf(o[df][r4]);
    }
}

// ---------------- host launch ----------------
extern "C" void kernel_launch(void* const* d_in, const int* in_sizes, int n_in,
                              void* d_out, int out_size, void* d_ws, size_t ws_size,
                              hipStream_t stream) {
  const float* x_in  = (const float*)d_in[0];
  const float* lnr_w = (const float*)d_in[1];
  const float* lnr_b = (const float*)d_in[2];
  const float* rq_w  = (const float*)d_in[3];
  const float* rq_b  = (const float*)d_in[4];
  const float* rk_w  = (const float*)d_in[5];
  const float* rk_b  = (const float*)d_in[6];
  const float* rv_w  = (const float*)d_in[7];
  const float* rv_b  = (const float*)d_in[8];
  const float* ro_w  = (const float*)d_in[9];
  const float* ro_b  = (const float*)d_in[10];
  const float* lnc_w = (const float*)d_in[11];
  const float* lnc_b = (const float*)d_in[12];
  const float* cq_w  = (const float*)d_in[13];
  const float* cq_b  = (const float*)d_in[14];
  const float* ck_w  = (const float*)d_in[15];
  const float* ck_b  = (const float*)d_in[16];
  const float* cv_w  = (const float*)d_in[17];
  const float* cv_b  = (const float*)d_in[18];
  const float* co_w  = (const float*)d_in[19];
  const float* co_b  = (const float*)d_in[20];
  const float* lnf_w = (const float*)d_in[21];
  const float* lnf_b = (const float*)d_in[22];
  const float* f1_w  = (const float*)d_in[23];
  const float* f1_b  = (const float*)d_in[24];
  const float* f2_w  = (const float*)d_in[25];
  const float* f2_b  = (const float*)d_in[26];

  const float s_row = 0.0127577591f;  // (96^-0.5)/8
  const float s_col = 0.1020620726f;  // 96^-0.5

  // ---- ws layout ----
  char* ws = (char*)d_ws;
  const size_t WSZ_E = 589824 * 2;        // one E x E bf16 weight
  u16* w_all = (u16*)ws;                  // rq,rk,rv | ro | cq,ck,cv | co | f1 | f2
  u16* w_rqkv = w_all;
  u16* w_ro   = (u16*)(ws + 3 * WSZ_E);
  u16* w_cqkv = (u16*)(ws + 4 * WSZ_E);
  u16* w_co   = (u16*)(ws + 7 * WSZ_E);
  u16* w_f1   = (u16*)(ws + 8 * WSZ_E);                 // 4,718,592 B
  u16* w_f2   = (u16*)(ws + 8 * WSZ_E + 4718592);       // 4,718,592 B
  size_t off = 8 * WSZ_E + 2 * 4718592;                 // 18,874,368

  const bool xf32 = ws_size >= 147849216ULL;            // f32 residual if it fits
  char* x_cur = ws + off;                               // f32 (50.3MB) or bf16 (25.2MB)
  off += xf32 ? 50331648 : 25165824;
  u16* qb = (u16*)(ws + off); off += 25165824;
  u16* kb = (u16*)(ws + off); off += 25165824;
  u16* vb = (u16*)(ws + off); off += 25165824;
  u16* probsb = (u16*)(ws + off); off += 1048576;       // bf16 row probs
  float* qkvb_row = (float*)(ws + off); off += 9216;    // [2304] f32
  float* qkvb_col = (float*)(ws + off); off += 9216;

  u16* vt     = qb;            // row-attn V^T overlays qb (free after logits)
  u16* ctx1   = kb;            // row-attn context overlays kb
  u16* hidden = qb;            // FFN hidden chunk (50.3MB) overlays qb+kb
  u16* xn3    = vb;            // stage-3 LN output overlays vb

  // ---- d_out layout + d_out-as-scratch ----
  float* out_x  = (float*)d_out;            // 12,582,912 f32 (free until final fc2)
  float* out_rp = out_x + 12582912;         // row_probs [8,1,256,256] f32
  float* out_cp = out_x + 13107200;         // col_probs [8,256,1,64,64] f32
  u16* xn   = (u16*)out_x;                  // LN out (stages 1,2), lower half of out_x
  u16* ctx2 = (u16*)((char*)out_x + 25165824);  // col-attn context, upper half
  float* part = out_x;                      // split-K logits partials (33.5MB, dead after softmax)

  const dim3 blk(256);

  // ---- weight conversion (one dispatch) + bias packs ----
  CvtArgs ca;
  ca.src[0] = rq_w; ca.src[1] = rk_w; ca.src[2] = rv_w; ca.src[3] = ro_w;
  ca.src[4] = cq_w; ca.src[5] = ck_w; ca.src[6] = cv_w; ca.src[7] = co_w;
  ca.src[8] = f1_w; ca.src[9] = f2_w;
  for (int i = 0; i < 10; ++i) ca.scale[i] = 1.f;
  ca.scale[0] = s_row; ca.scale[4] = s_col;
  cvt_all<<<9216, blk, 0, stream>>>(ca, w_all);
  bias_pack<<<9, blk, 0, stream>>>(rq_b, rk_b, rv_b, s_row, qkvb_row);
  bias_pack<<<9, blk, 0, stream>>>(cq_b, ck_b, cv_b, s_col, qkvb_col);

  // ---- Stage 1: row attention ----
  ln_kernel<true><<<4096, blk, 0, stream>>>(x_in, lnr_w, lnr_b, xn);
  gemm_bt<0, 8><<<dim3(128, 18, 1), blk, 0, stream>>>(xn, w_rqkv, qkvb_row, nullptr, qb, 768, 768, 768, 0, 0, 0, 768, 1.f);
  // split-K logits: grid.z = h*16+s, partials into d_out scratch (xn is dead now)
  gemm_bt<2, 1><<<dim3(2, 2, 128), blk, 0, stream>>>(qb, kb, nullptr, nullptr, part, 384, 0, 0, 0, 0, 65536LL, 256, 1.f);
  softmax_row<<<512, blk, 0, stream>>>(part, out_rp, probsb);
  pack_vt<<<dim3(4, 64, 8), blk, 0, stream>>>(vb, vt);
  gemm_bt<0, 7><<<dim3(2, 48, 8), blk, 0, stream>>>(probsb, vt, nullptr, nullptr, ctx1, 256, 256, 256, 65536LL, 1572864LL, 0, 0, 1.f);
  if (xf32)
    gemm_bt<0, 3><<<dim3(128, 6, 1), blk, 0, stream>>>(ctx1, w_ro, ro_b, x_in, x_cur, 768, 768, 768, 0, 0, 0, 768, 1.f);
  else
    gemm_bt<0, 4><<<dim3(128, 6, 1), blk, 0, stream>>>(ctx1, w_ro, ro_b, x_in, x_cur, 768, 768, 768, 0, 0, 0, 768, 1.f);

  // ---- Stage 2: column attention ----
  if (xf32) ln_kernel<true><<<4096, blk, 0, stream>>>(x_cur, lnc_w, lnc_b, xn);
  else      ln_kernel<false><<<4096, blk, 0, stream>>>(x_cur, lnc_w, lnc_b, xn);
  gemm_bt<0, 8><<<dim3(128, 18, 1), blk, 0, stream>>>(xn, w_cqkv, qkvb_col, nullptr, qb, 768, 768, 768, 0, 0, 0, 768, 1.f);
  col_attn<<<dim3(256, 8), blk, 0, stream>>>(qb, kb, vb, out_cp, ctx2);
  if (xf32)
    gemm_bt<0, 3><<<dim3(128, 6, 1), blk, 0, stream>>>(ctx2, w_co, co_b, x_cur, x_cur, 768, 768, 768, 0, 0, 0, 768, 1.f);
  else
    gemm_bt<0, 6><<<dim3(128, 6, 1), blk, 0, stream>>>(ctx2, w_co, co_b, x_cur, x_cur, 768, 768, 768, 0, 0, 0, 768, 1.f);

  // ---- Stage 3: FFN (F chunked 2x1536 so hidden fits qb+kb) ----
  if (xf32) ln_kernel<true><<<4096, blk, 0, stream>>>(x_cur, lnf_w, lnf_b, xn3);
  else      ln_kernel<false><<<4096, blk, 0, stream>>>(x_cur, lnf_w, lnf_b, xn3);
  // chunk 0
  gemm_bt<0, 2><<<dim3(128, 12, 1), blk, 0, stream>>>(xn3, w_f1, f1_b, nullptr, hidden, 768, 768, 768, 0, 0, 0, 1536, 1.f);
  if (xf32)
    gemm_bt<0, 3><<<dim3(128, 6, 1), blk, 0, stream>>>(hidden, w_f2, f2_b, x_cur, out_x, 1536, 1536, 3072, 0, 0, 0, 768, 1.f);
  else
    gemm_bt<0, 5><<<dim3(128, 6, 1), blk, 0, stream>>>(hidden, w_f2, f2_b, x_cur, out_x, 1536, 1536, 3072, 0, 0, 0, 768, 1.f);
  // chunk 1 (accumulate into out_x)
  gemm_bt<0, 2><<<dim3(128, 12, 1), blk, 0, stream>>>(xn3, w_f1 + 1536 * 768, f1_b + 1536, nullptr, hidden, 768, 768, 768, 0, 0, 0, 1536, 1.f);
  gemm_bt<0, 3><<<dim3(128, 6, 1), blk, 0, stream>>>(hidden, w_f2 + 1536, nullptr, out_x, out_x, 1536, 1536, 3072, 0, 0, 0, 768, 1.f);
}

// Round 5
// 664.723 us; speedup vs baseline: 1.2465x; 1.2465x over previous
//
#include <hip/hip_runtime.h>
#include <cstdint>

typedef unsigned short u16;
typedef __attribute__((ext_vector_type(8))) short short8;   // 8 x bf16 (4 VGPR)
typedef __attribute__((ext_vector_type(4))) short short4v;  // 4 x bf16
typedef __attribute__((ext_vector_type(4))) float floatx4;  // MFMA acc / float4

#define DEV __device__ __forceinline__

DEV float bf2f(u16 u) { union { uint32_t i; float f; } w; w.i = ((uint32_t)u) << 16; return w.f; }
DEV u16 f2bf(float f) {
  union { float f; uint32_t i; } w; w.f = f;
  uint32_t x = w.i;
  return (u16)((x + 0x7fffu + ((x >> 16) & 1u)) >> 16);  // RNE
}

// fast exact-gelu: A&S 7.1.26 erf approx, |err|<=1.5e-7, branchless
DEV float fast_gelu(float x) {
  const float y = x * 0.70710678118f;
  const float ay = fabsf(y);
  const float t = 1.f / (1.f + 0.3275911f * ay);
  const float poly = t * (0.254829592f + t * (-0.284496736f +
                     t * (1.421413741f + t * (-1.453152027f + t * 1.061405429f))));
  const float er = 1.f - poly * __expf(-y * y);
  const float erf_y = __builtin_copysignf(er, y);
  return 0.5f * x * (1.f + erf_y);
}

// async global->LDS, 16B per lane. LDS dest must be wave-uniform base; HW adds lane*16.
DEV void async_copy16(const u16* g, u16* l) {
  __builtin_amdgcn_global_load_lds(
      (const __attribute__((address_space(1))) void*)(uintptr_t)g,
      (__attribute__((address_space(3))) void*)(uint32_t)(uintptr_t)l,
      16, 0, 0);
}

// ---------------- fused f32 -> bf16 weight convert (all 10 weights) ----------------
// dst layout (contiguous): rq,rk,rv,ro,cq,ck,cv,co (589824 each), f1,f2 (2359296 each)
struct CvtArgs {
  const float* src[10];
  float scale[10];
};
__global__ __launch_bounds__(256) void cvt_all(CvtArgs a, u16* __restrict__ dst) {
  const size_t e = ((size_t)blockIdx.x * 256 + threadIdx.x) * 4;  // 9437184 total elems
  if (e >= 9437184) return;
  int reg;
  size_t base;
  if (e < 4718592) { reg = (int)(e / 589824); base = (size_t)reg * 589824; }
  else if (e < 7077888) { reg = 8; base = 4718592; }
  else { reg = 9; base = 7077888; }
  const float sc = a.scale[reg];
  floatx4 f = *(const floatx4*)(a.src[reg] + (e - base));
  short4v o;
#pragma unroll
  for (int j = 0; j < 4; ++j) o[j] = (short)f2bf(f[j] * sc);
  *(short4v*)(dst + e) = o;
}

// pack q/k/v biases into one [2304] f32 buffer per stage, q part pre-scaled
__global__ __launch_bounds__(256) void bias_pack(const float* __restrict__ qb,
                                                 const float* __restrict__ kb,
                                                 const float* __restrict__ vb,
                                                 float sq, float* __restrict__ out) {
  const int i = blockIdx.x * 256 + threadIdx.x;
  if (i >= 2304) return;
  const int buf = i / 768, c = i - buf * 768;
  out[i] = buf == 0 ? qb[c] * sq : (buf == 1 ? kb[c] : vb[c]);
}

// ---------------- LayerNorm: one wave per row of 768, bf16 out ----------------
template<bool INF32>
__global__ __launch_bounds__(256) void ln_kernel(const void* __restrict__ in,
                                                 const float* __restrict__ w,
                                                 const float* __restrict__ b,
                                                 u16* __restrict__ out) {
  const int wid = threadIdx.x >> 6, lane = threadIdx.x & 63;
  const int row = blockIdx.x * 4 + wid;  // 16384 rows
  const size_t base = (size_t)row * 768;
  float v[12];
#pragma unroll
  for (int p = 0; p < 3; ++p) {
    const int e = p * 256 + lane * 4;
    if constexpr (INF32) {
      floatx4 f = *(const floatx4*)((const float*)in + base + e);
#pragma unroll
      for (int j = 0; j < 4; ++j) v[p * 4 + j] = f[j];
    } else {
      short4v u = *(const short4v*)((const u16*)in + base + e);
#pragma unroll
      for (int j = 0; j < 4; ++j) v[p * 4 + j] = bf2f((u16)u[j]);
    }
  }
  float s = 0.f, sq = 0.f;
#pragma unroll
  for (int i = 0; i < 12; ++i) { s += v[i]; sq += v[i] * v[i]; }
#pragma unroll
  for (int m = 1; m < 64; m <<= 1) { s += __shfl_xor(s, m); sq += __shfl_xor(sq, m); }
  const float mean = s * (1.f / 768.f);
  const float var = sq * (1.f / 768.f) - mean * mean;
  const float rstd = rsqrtf(var + 1e-5f);
#pragma unroll
  for (int p = 0; p < 3; ++p) {
    const int e = p * 256 + lane * 4;
    floatx4 wv = *(const floatx4*)(w + e);
    floatx4 bv = *(const floatx4*)(b + e);
    short4v o;
#pragma unroll
    for (int j = 0; j < 4; ++j) {
      float y = (v[p * 4 + j] - mean) * rstd * wv[j] + bv[j];
      o[j] = (short)f2bf(y);
    }
    *(short4v*)(out + base + e) = o;
  }
}

// ---------------- GEMM: C[M,N] = A[M,K] * B[N,K]^T (+epilogue) ----------------
// 128x128 tile, BK=32, 4 waves (2x2), mfma_f32_16x16x32_bf16, global_load_lds staging.
// AMODE: 0 = normal strides lda/ldb
//        1 = row-attn logits addressing: elem(row,kk) = base + z*96 + (kk/96)*196608 + row*768 + (kk%96)
//        2 = split-K row-attn logits: z = h*16+s, head h, K-window [s*384, s*384+384)
// EPI: 1 f32=acc | 2 bf16=gelu(acc+bz) | 3 f32=resf32+acc+bz | 4 bf16=resf32+acc+bz
//      5 f32=resbf16+acc+bz | 6 bf16=resbf16+acc+bz
//      7 bf16 scatter (row-attn PV): n=(r*96+d) -> out[(r*256+m)*768 + z*96 + d]
//      8 bf16 merged-QKV split write: buf=n/768 -> out + buf*12582912 + m*768 + (n%768)
template<int AMODE, int EPI>
__global__ __launch_bounds__(256) void gemm_bt(
    const u16* __restrict__ A, const u16* __restrict__ B,
    const float* __restrict__ bias, const void* __restrict__ res,
    void* __restrict__ out, int K, int lda, int ldb,
    long long aBatch, long long bBatch, long long outBatch, int ldc, float scale) {
  __shared__ u16 lA[128 * 32];
  __shared__ u16 lB[128 * 32];
  const int t = threadIdx.x;
  const int z = blockIdx.z;
  const int m0 = blockIdx.x * 128, n0 = blockIdx.y * 128;
  const u16* Ab;
  const u16* Bb;
  int koff = 0;
  if constexpr (AMODE == 0) { Ab = A + (size_t)z * aBatch; Bb = B + (size_t)z * bBatch; }
  else if constexpr (AMODE == 1) { Ab = A + z * 96; Bb = B + z * 96; }
  else { const int h = z >> 4; Ab = A + h * 96; Bb = B + h * 96; koff = (z & 15) * 384; }

  const int krow = t >> 2;          // 0..63
  const int kcol = (t & 3) << 3;    // 0,8,16,24
  const int wid = t >> 6, lane = t & 63;
  const int wr = wid >> 1, wc = wid & 1;
  const int lrow = lane & 15, lhi = lane >> 4;

  floatx4 acc[4][4];
#pragma unroll
  for (int i = 0; i < 4; ++i)
#pragma unroll
    for (int j = 0; j < 4; ++j) acc[i][j] = (floatx4){0.f, 0.f, 0.f, 0.f};

  for (int k0 = 0; k0 < K; k0 += 32) {
#pragma unroll
    for (int i = 0; i < 2; ++i) {
      const int row = i * 64 + krow;
      const int kk = koff + k0 + kcol;
      const u16 *ga, *gb;
      if constexpr (AMODE == 0) {
        ga = Ab + (size_t)(m0 + row) * lda + kk;
        gb = Bb + (size_t)(n0 + row) * ldb + kk;
      } else {
        const int r = kk / 96, d = kk - r * 96;  // 8|96 so a lane's 8-chunk never crosses r
        ga = Ab + (size_t)r * 196608 + (size_t)(m0 + row) * 768 + d;
        gb = Bb + (size_t)r * 196608 + (size_t)(n0 + row) * 768 + d;
      }
      async_copy16(ga, lA + i * 2048 + wid * 512);
      async_copy16(gb, lB + i * 2048 + wid * 512);
    }
    asm volatile("s_waitcnt vmcnt(0)" ::: "memory");
    __syncthreads();

    short8 af[4], bfr[4];
#pragma unroll
    for (int mi = 0; mi < 4; ++mi)
      af[mi] = *(const short8*)&lA[(wr * 64 + mi * 16 + lrow) * 32 + lhi * 8];
#pragma unroll
    for (int ni = 0; ni < 4; ++ni)
      bfr[ni] = *(const short8*)&lB[(wc * 64 + ni * 16 + lrow) * 32 + lhi * 8];
#pragma unroll
    for (int mi = 0; mi < 4; ++mi)
#pragma unroll
      for (int ni = 0; ni < 4; ++ni)
        acc[mi][ni] = __builtin_amdgcn_mfma_f32_16x16x32_bf16(af[mi], bfr[ni], acc[mi][ni], 0, 0, 0);
    __syncthreads();
  }

  const int mbase = m0 + wr * 64;
  const int nbase = n0 + wc * 64;
#pragma unroll
  for (int mi = 0; mi < 4; ++mi) {
#pragma unroll
    for (int ni = 0; ni < 4; ++ni) {
      const int n = nbase + ni * 16 + lrow;
      float bz = 0.f;
      if constexpr (EPI != 1 && EPI != 7) { if (bias) bz = bias[n]; }
#pragma unroll
      for (int r4 = 0; r4 < 4; ++r4) {
        const int m = mbase + mi * 16 + lhi * 4 + r4;
        const float val = acc[mi][ni][r4];
        if constexpr (EPI == 1) {
          ((float*)out)[(size_t)z * outBatch + (size_t)m * ldc + n] = val;
        } else if constexpr (EPI == 2) {
          ((u16*)out)[(size_t)m * ldc + n] = f2bf(fast_gelu(val + bz));
        } else if constexpr (EPI == 3) {
          const float r = ((const float*)res)[(size_t)m * ldc + n];
          ((float*)out)[(size_t)m * ldc + n] = r + val + bz;
        } else if constexpr (EPI == 4) {
          const float r = ((const float*)res)[(size_t)m * ldc + n];
          ((u16*)out)[(size_t)m * ldc + n] = f2bf(r + val + bz);
        } else if constexpr (EPI == 5) {
          const float r = bf2f(((const u16*)res)[(size_t)m * ldc + n]);
          ((float*)out)[(size_t)m * ldc + n] = r + val + bz;
        } else if constexpr (EPI == 6) {
          const float r = bf2f(((const u16*)res)[(size_t)m * ldc + n]);
          ((u16*)out)[(size_t)m * ldc + n] = f2bf(r + val + bz);
        } else if constexpr (EPI == 7) {
          const int rr = n / 96, d = n - rr * 96;
          ((u16*)out)[((size_t)(rr * 256 + m)) * 768 + (size_t)z * 96 + d] = f2bf(val);
        } else if constexpr (EPI == 8) {
          const int buf = n / 768, col = n - buf * 768;
          ((u16*)out)[(size_t)buf * 12582912 + (size_t)m * 768 + col] = f2bf(val + bz);
        }
      }
    }
  }
}

// ---------------- row softmax fused with split-K reduce ----------------
// part[(h*16+s)*65536 + i*256 + j]; row = h*256+i; 2048 rows, one wave per row.
__global__ __launch_bounds__(256) void softmax_row(const float* __restrict__ part,
                                                   float* __restrict__ probs_f,
                                                   u16* __restrict__ probs_b) {
  const int wid = threadIdx.x >> 6, lane = threadIdx.x & 63;
  const int row = blockIdx.x * 4 + wid;
  const int h = row >> 8, i = row & 255;
  const size_t base = (size_t)h * 16 * 65536 + (size_t)i * 256 + lane * 4;
  floatx4 v = (floatx4){0.f, 0.f, 0.f, 0.f};
#pragma unroll
  for (int s16 = 0; s16 < 16; ++s16) {
    floatx4 p = *(const floatx4*)(part + base + (size_t)s16 * 65536);
#pragma unroll
    for (int j = 0; j < 4; ++j) v[j] += p[j];
  }
  float mx = fmaxf(fmaxf(v[0], v[1]), fmaxf(v[2], v[3]));
#pragma unroll
  for (int m = 1; m < 64; m <<= 1) mx = fmaxf(mx, __shfl_xor(mx, m));
  float e[4], s = 0.f;
#pragma unroll
  for (int j = 0; j < 4; ++j) { e[j] = __expf(v[j] - mx); s += e[j]; }
#pragma unroll
  for (int m = 1; m < 64; m <<= 1) s += __shfl_xor(s, m);
  const float inv = 1.f / s;
  floatx4 of;
  short4v ob;
#pragma unroll
  for (int j = 0; j < 4; ++j) {
    const float p = e[j] * inv;
    of[j] = p;
    ob[j] = (short)f2bf(p);
  }
  *(floatx4*)(probs_f + (size_t)row * 256 + lane * 4) = of;
  *(short4v*)(probs_b + (size_t)row * 256 + lane * 4) = ob;
}

// ---------------- pack V^T for row-attn PV: vt[h][(r*96+d)][j] = v[(r*256+j)*768+h*96+d]
__global__ __launch_bounds__(256) void pack_vt(const u16* __restrict__ v, u16* __restrict__ vt) {
  __shared__ u16 S[64][104];  // [j][d], padded
  const int jb = blockIdx.x, r = blockIdx.y, h = blockIdx.z;
  const int t = threadIdx.x;
#pragma unroll
  for (int p = 0; p < 3; ++p) {
    const int cid = t + p * 256;
    const int j = cid / 12, ch = cid - j * 12;
    short8 x = *(const short8*)&v[((size_t)(r * 256 + jb * 64 + j)) * 768 + h * 96 + ch * 8];
    *(short8*)&S[j][ch * 8] = x;
  }
  __syncthreads();
#pragma unroll
  for (int p = 0; p < 3; ++p) {
    const int cid = t + p * 256;
    const int d = cid / 8, cj = cid - d * 8;
    u16 tmp[8];
#pragma unroll
    for (int m = 0; m < 8; ++m) tmp[m] = S[cj * 8 + m][d];
    *(short8*)&vt[((size_t)(h * 6144 + r * 96 + d)) * 256 + jb * 64 + cj * 8] = *(short8*)tmp;
  }
}

// ---------------- fused column attention: one block per (c, h) ----------------
__global__ __launch_bounds__(256) void col_attn(const u16* __restrict__ q,
                                                const u16* __restrict__ k,
                                                const u16* __restrict__ v,
                                                float* __restrict__ probs,
                                                u16* __restrict__ ctx) {
  __shared__ u16 qs[64][104];
  __shared__ u16 ks[64][104];
  __shared__ u16 vt[96][72];
  __shared__ u16 ps[64][72];
  const int c = blockIdx.x, h = blockIdx.y;
  const int t = threadIdx.x;
#pragma unroll
  for (int p = 0; p < 3; ++p) {
    const int cid = t + p * 256;
    const int i = cid / 12, ch = cid - i * 12;
    const size_t g = ((size_t)(i * 256 + c)) * 768 + h * 96 + ch * 8;
    short8 qv = *(const short8*)(q + g);
    short8 kv = *(const short8*)(k + g);
    short8 vv = *(const short8*)(v + g);
    *(short8*)&qs[i][ch * 8] = qv;
    *(short8*)&ks[i][ch * 8] = kv;
#pragma unroll
    for (int m = 0; m < 8; ++m) vt[ch * 8 + m][i] = (u16)vv[m];
  }
  __syncthreads();
  const int lane = t & 63, wid = t >> 6;
  const int lrow = lane & 15, lhi = lane >> 4;

  floatx4 s[4];
#pragma unroll
  for (int nj = 0; nj < 4; ++nj) s[nj] = (floatx4){0.f, 0.f, 0.f, 0.f};
#pragma unroll
  for (int kk = 0; kk < 3; ++kk) {
    short8 a = *(const short8*)&qs[wid * 16 + lrow][kk * 32 + lhi * 8];
#pragma unroll
    for (int nj = 0; nj < 4; ++nj) {
      short8 bb = *(const short8*)&ks[nj * 16 + lrow][kk * 32 + lhi * 8];
      s[nj] = __builtin_amdgcn_mfma_f32_16x16x32_bf16(a, bb, s[nj], 0, 0, 0);
    }
  }
  const size_t pb = ((size_t)(h * 256 + c)) * 4096;
#pragma unroll
  for (int r4 = 0; r4 < 4; ++r4) {
    float mx = fmaxf(fmaxf(s[0][r4], s[1][r4]), fmaxf(s[2][r4], s[3][r4]));
    mx = fmaxf(mx, __shfl_xor(mx, 1));
    mx = fmaxf(mx, __shfl_xor(mx, 2));
    mx = fmaxf(mx, __shfl_xor(mx, 4));
    mx = fmaxf(mx, __shfl_xor(mx, 8));
    float e[4], sum = 0.f;
#pragma unroll
    for (int nj = 0; nj < 4; ++nj) { e[nj] = __expf(s[nj][r4] - mx); sum += e[nj]; }
    sum += __shfl_xor(sum, 1);
    sum += __shfl_xor(sum, 2);
    sum += __shfl_xor(sum, 4);
    sum += __shfl_xor(sum, 8);
    const float inv = 1.f / sum;
    const int i = wid * 16 + lhi * 4 + r4;
#pragma unroll
    for (int nj = 0; nj < 4; ++nj) {
      const float pv = e[nj] * inv;
      const int j = nj * 16 + lrow;
      probs[pb + (size_t)i * 64 + j] = pv;
      ps[i][j] = f2bf(pv);
    }
  }
  __syncthreads();
  floatx4 o[6];
#pragma unroll
  for (int df = 0; df < 6; ++df) o[df] = (floatx4){0.f, 0.f, 0.f, 0.f};
#pragma unroll
  for (int k2 = 0; k2 < 2; ++k2) {
    short8 a = *(const short8*)&ps[wid * 16 + lrow][k2 * 32 + lhi * 8];
#pragma unroll
    for (int df = 0; df < 6; ++df) {
      short8 bb = *(const short8*)&vt[df * 16 + lrow][k2 * 32 + lhi * 8];
      o[df] = __builtin_amdgcn_mfma_f32_16x16x32_bf16(a, bb, o[df], 0, 0, 0);
    }
  }
#pragma unroll
  for (int df = 0; df < 6; ++df)
#pragma unroll
    for (int r4 = 0; r4 < 4; ++r4) {
      const int i = wid * 16 + lhi * 4 + r4;
      const int d = df * 16 + lrow;
      ctx[((size_t)(i * 256 + c)) * 768 + h * 96 + d] = f2bf(o[df][r4]);
    }
}

// ---------------- host launch ----------------
extern "C" void kernel_launch(void* const* d_in, const int* in_sizes, int n_in,
                              void* d_out, int out_size, void* d_ws, size_t ws_size,
                              hipStream_t stream) {
  const float* x_in  = (const float*)d_in[0];
  const float* lnr_w = (const float*)d_in[1];
  const float* lnr_b = (const float*)d_in[2];
  const float* rq_w  = (const float*)d_in[3];
  const float* rq_b  = (const float*)d_in[4];
  const float* rk_w  = (const float*)d_in[5];
  const float* rk_b  = (const float*)d_in[6];
  const float* rv_w  = (const float*)d_in[7];
  const float* rv_b  = (const float*)d_in[8];
  const float* ro_w  = (const float*)d_in[9];
  const float* ro_b  = (const float*)d_in[10];
  const float* lnc_w = (const float*)d_in[11];
  const float* lnc_b = (const float*)d_in[12];
  const float* cq_w  = (const float*)d_in[13];
  const float* cq_b  = (const float*)d_in[14];
  const float* ck_w  = (const float*)d_in[15];
  const float* ck_b  = (const float*)d_in[16];
  const float* cv_w  = (const float*)d_in[17];
  const float* cv_b  = (const float*)d_in[18];
  const float* co_w  = (const float*)d_in[19];
  const float* co_b  = (const float*)d_in[20];
  const float* lnf_w = (const float*)d_in[21];
  const float* lnf_b = (const float*)d_in[22];
  const float* f1_w  = (const float*)d_in[23];
  const float* f1_b  = (const float*)d_in[24];
  const float* f2_w  = (const float*)d_in[25];
  const float* f2_b  = (const float*)d_in[26];

  const float s_row = 0.0127577591f;  // (96^-0.5)/8
  const float s_col = 0.1020620726f;  // 96^-0.5

  // ---- ws layout ----
  char* ws = (char*)d_ws;
  const size_t WSZ_E = 589824 * 2;        // one E x E bf16 weight
  u16* w_all = (u16*)ws;                  // rq,rk,rv | ro | cq,ck,cv | co | f1 | f2
  u16* w_rqkv = w_all;
  u16* w_ro   = (u16*)(ws + 3 * WSZ_E);
  u16* w_cqkv = (u16*)(ws + 4 * WSZ_E);
  u16* w_co   = (u16*)(ws + 7 * WSZ_E);
  u16* w_f1   = (u16*)(ws + 8 * WSZ_E);                 // 4,718,592 B
  u16* w_f2   = (u16*)(ws + 8 * WSZ_E + 4718592);       // 4,718,592 B
  size_t off = 8 * WSZ_E + 2 * 4718592;                 // 18,874,368

  const bool xf32 = ws_size >= 147849216ULL;            // f32 residual if it fits
  char* x_cur = ws + off;                               // f32 (50.3MB) or bf16 (25.2MB)
  off += xf32 ? 50331648 : 25165824;
  u16* qb = (u16*)(ws + off); off += 25165824;
  u16* kb = (u16*)(ws + off); off += 25165824;
  u16* vb = (u16*)(ws + off); off += 25165824;
  u16* probsb = (u16*)(ws + off); off += 1048576;       // bf16 row probs
  float* qkvb_row = (float*)(ws + off); off += 9216;    // [2304] f32
  float* qkvb_col = (float*)(ws + off); off += 9216;

  u16* vt     = qb;            // row-attn V^T overlays qb (free after logits)
  u16* ctx1   = kb;            // row-attn context overlays kb
  u16* hidden = qb;            // FFN hidden chunk (50.3MB) overlays qb+kb
  u16* xn3    = vb;            // stage-3 LN output overlays vb

  // ---- d_out layout + d_out-as-scratch ----
  float* out_x  = (float*)d_out;            // 12,582,912 f32 (free until final fc2)
  float* out_rp = out_x + 12582912;         // row_probs [8,1,256,256] f32
  float* out_cp = out_x + 13107200;         // col_probs [8,256,1,64,64] f32
  u16* xn   = (u16*)out_x;                  // LN out (stages 1,2), lower half of out_x
  u16* ctx2 = (u16*)((char*)out_x + 25165824);  // col-attn context, upper half
  float* part = out_x;                      // split-K logits partials (33.5MB, dead after softmax)

  const dim3 blk(256);

  // ---- weight conversion (one dispatch) + bias packs ----
  CvtArgs ca;
  ca.src[0] = rq_w; ca.src[1] = rk_w; ca.src[2] = rv_w; ca.src[3] = ro_w;
  ca.src[4] = cq_w; ca.src[5] = ck_w; ca.src[6] = cv_w; ca.src[7] = co_w;
  ca.src[8] = f1_w; ca.src[9] = f2_w;
  for (int i = 0; i < 10; ++i) ca.scale[i] = 1.f;
  ca.scale[0] = s_row; ca.scale[4] = s_col;
  cvt_all<<<9216, blk, 0, stream>>>(ca, w_all);
  bias_pack<<<9, blk, 0, stream>>>(rq_b, rk_b, rv_b, s_row, qkvb_row);
  bias_pack<<<9, blk, 0, stream>>>(cq_b, ck_b, cv_b, s_col, qkvb_col);

  // ---- Stage 1: row attention ----
  ln_kernel<true><<<4096, blk, 0, stream>>>(x_in, lnr_w, lnr_b, xn);
  gemm_bt<0, 8><<<dim3(128, 18, 1), blk, 0, stream>>>(xn, w_rqkv, qkvb_row, nullptr, qb, 768, 768, 768, 0, 0, 0, 768, 1.f);
  // split-K logits: grid.z = h*16+s, partials into d_out scratch (xn is dead now)
  gemm_bt<2, 1><<<dim3(2, 2, 128), blk, 0, stream>>>(qb, kb, nullptr, nullptr, part, 384, 0, 0, 0, 0, 65536LL, 256, 1.f);
  softmax_row<<<512, blk, 0, stream>>>(part, out_rp, probsb);
  pack_vt<<<dim3(4, 64, 8), blk, 0, stream>>>(vb, vt);
  gemm_bt<0, 7><<<dim3(2, 48, 8), blk, 0, stream>>>(probsb, vt, nullptr, nullptr, ctx1, 256, 256, 256, 65536LL, 1572864LL, 0, 0, 1.f);
  if (xf32)
    gemm_bt<0, 3><<<dim3(128, 6, 1), blk, 0, stream>>>(ctx1, w_ro, ro_b, x_in, x_cur, 768, 768, 768, 0, 0, 0, 768, 1.f);
  else
    gemm_bt<0, 4><<<dim3(128, 6, 1), blk, 0, stream>>>(ctx1, w_ro, ro_b, x_in, x_cur, 768, 768, 768, 0, 0, 0, 768, 1.f);

  // ---- Stage 2: column attention ----
  if (xf32) ln_kernel<true><<<4096, blk, 0, stream>>>(x_cur, lnc_w, lnc_b, xn);
  else      ln_kernel<false><<<4096, blk, 0, stream>>>(x_cur, lnc_w, lnc_b, xn);
  gemm_bt<0, 8><<<dim3(128, 18, 1), blk, 0, stream>>>(xn, w_cqkv, qkvb_col, nullptr, qb, 768, 768, 768, 0, 0, 0, 768, 1.f);
  col_attn<<<dim3(256, 8), blk, 0, stream>>>(qb, kb, vb, out_cp, ctx2);
  if (xf32)
    gemm_bt<0, 3><<<dim3(128, 6, 1), blk, 0, stream>>>(ctx2, w_co, co_b, x_cur, x_cur, 768, 768, 768, 0, 0, 0, 768, 1.f);
  else
    gemm_bt<0, 6><<<dim3(128, 6, 1), blk, 0, stream>>>(ctx2, w_co, co_b, x_cur, x_cur, 768, 768, 768, 0, 0, 0, 768, 1.f);

  // ---- Stage 3: FFN (F chunked 2x1536 so hidden fits qb+kb) ----
  if (xf32) ln_kernel<true><<<4096, blk, 0, stream>>>(x_cur, lnf_w, lnf_b, xn3);
  else      ln_kernel<false><<<4096, blk, 0, stream>>>(x_cur, lnf_w, lnf_b, xn3);
  // chunk 0
  gemm_bt<0, 2><<<dim3(128, 12, 1), blk, 0, stream>>>(xn3, w_f1, f1_b, nullptr, hidden, 768, 768, 768, 0, 0, 0, 1536, 1.f);
  if (xf32)
    gemm_bt<0, 3><<<dim3(128, 6, 1), blk, 0, stream>>>(hidden, w_f2, f2_b, x_cur, out_x, 1536, 1536, 3072, 0, 0, 0, 768, 1.f);
  else
    gemm_bt<0, 5><<<dim3(128, 6, 1), blk, 0, stream>>>(hidden, w_f2, f2_b, x_cur, out_x, 1536, 1536, 3072, 0, 0, 0, 768, 1.f);
  // chunk 1 (accumulate into out_x)
  gemm_bt<0, 2><<<dim3(128, 12, 1), blk, 0, stream>>>(xn3, w_f1 + 1536 * 768, f1_b + 1536, nullptr, hidden, 768, 768, 768, 0, 0, 0, 1536, 1.f);
  gemm_bt<0, 3><<<dim3(128, 6, 1), blk, 0, stream>>>(hidden, w_f2 + 1536, nullptr, out_x, out_x, 1536, 1536, 3072, 0, 0, 0, 768, 1.f);
}

// Round 6
// 662.579 us; speedup vs baseline: 1.2505x; 1.0032x over previous
//
#include <hip/hip_runtime.h>
#include <cstdint>

typedef unsigned short u16;
typedef __attribute__((ext_vector_type(8))) short short8;   // 8 x bf16 (4 VGPR)
typedef __attribute__((ext_vector_type(4))) short short4v;  // 4 x bf16
typedef __attribute__((ext_vector_type(4))) float floatx4;  // MFMA acc / float4

#define DEV __device__ __forceinline__

DEV float bf2f(u16 u) { union { uint32_t i; float f; } w; w.i = ((uint32_t)u) << 16; return w.f; }
DEV u16 f2bf(float f) {
  union { float f; uint32_t i; } w; w.f = f;
  uint32_t x = w.i;
  return (u16)((x + 0x7fffu + ((x >> 16) & 1u)) >> 16);  // RNE
}

// fast exact-gelu: A&S 7.1.26 erf approx, |err|<=1.5e-7, branchless
DEV float fast_gelu(float x) {
  const float y = x * 0.70710678118f;
  const float ay = fabsf(y);
  const float t = 1.f / (1.f + 0.3275911f * ay);
  const float poly = t * (0.254829592f + t * (-0.284496736f +
                     t * (1.421413741f + t * (-1.453152027f + t * 1.061405429f))));
  const float er = 1.f - poly * __expf(-y * y);
  const float erf_y = __builtin_copysignf(er, y);
  return 0.5f * x * (1.f + erf_y);
}

// async global->LDS, 16B per lane. LDS dest must be wave-uniform base; HW adds lane*16.
DEV void async_copy16(const u16* g, u16* l) {
  __builtin_amdgcn_global_load_lds(
      (const __attribute__((address_space(1))) void*)(uintptr_t)g,
      (__attribute__((address_space(3))) void*)(uint32_t)(uintptr_t)l,
      16, 0, 0);
}

// ---------------- fused f32 -> bf16 weight convert (all 10 weights) ----------------
// dst layout (contiguous): rq,rk,rv,ro,cq,ck,cv,co (589824 each), f1,f2 (2359296 each)
struct CvtArgs {
  const float* src[10];
  float scale[10];
};
__global__ __launch_bounds__(256) void cvt_all(CvtArgs a, u16* __restrict__ dst) {
  const size_t e = ((size_t)blockIdx.x * 256 + threadIdx.x) * 4;  // 9437184 total elems
  if (e >= 9437184) return;
  int reg;
  size_t base;
  if (e < 4718592) { reg = (int)(e / 589824); base = (size_t)reg * 589824; }
  else if (e < 7077888) { reg = 8; base = 4718592; }
  else { reg = 9; base = 7077888; }
  const float sc = a.scale[reg];
  floatx4 f = *(const floatx4*)(a.src[reg] + (e - base));
  short4v o;
#pragma unroll
  for (int j = 0; j < 4; ++j) o[j] = (short)f2bf(f[j] * sc);
  *(short4v*)(dst + e) = o;
}

// pack q/k/v biases into one [2304] f32 buffer per stage, q part pre-scaled
__global__ __launch_bounds__(256) void bias_pack(const float* __restrict__ qb,
                                                 const float* __restrict__ kb,
                                                 const float* __restrict__ vb,
                                                 float sq, float* __restrict__ out) {
  const int i = blockIdx.x * 256 + threadIdx.x;
  if (i >= 2304) return;
  const int buf = i / 768, c = i - buf * 768;
  out[i] = buf == 0 ? qb[c] * sq : (buf == 1 ? kb[c] : vb[c]);
}

// ---------------- LayerNorm: one wave per row of 768, bf16 out ----------------
template<bool INF32>
__global__ __launch_bounds__(256) void ln_kernel(const void* __restrict__ in,
                                                 const float* __restrict__ w,
                                                 const float* __restrict__ b,
                                                 u16* __restrict__ out) {
  const int wid = threadIdx.x >> 6, lane = threadIdx.x & 63;
  const int row = blockIdx.x * 4 + wid;  // 16384 rows
  const size_t base = (size_t)row * 768;
  float v[12];
#pragma unroll
  for (int p = 0; p < 3; ++p) {
    const int e = p * 256 + lane * 4;
    if constexpr (INF32) {
      floatx4 f = *(const floatx4*)((const float*)in + base + e);
#pragma unroll
      for (int j = 0; j < 4; ++j) v[p * 4 + j] = f[j];
    } else {
      short4v u = *(const short4v*)((const u16*)in + base + e);
#pragma unroll
      for (int j = 0; j < 4; ++j) v[p * 4 + j] = bf2f((u16)u[j]);
    }
  }
  float s = 0.f, sq = 0.f;
#pragma unroll
  for (int i = 0; i < 12; ++i) { s += v[i]; sq += v[i] * v[i]; }
#pragma unroll
  for (int m = 1; m < 64; m <<= 1) { s += __shfl_xor(s, m); sq += __shfl_xor(sq, m); }
  const float mean = s * (1.f / 768.f);
  const float var = sq * (1.f / 768.f) - mean * mean;
  const float rstd = rsqrtf(var + 1e-5f);
#pragma unroll
  for (int p = 0; p < 3; ++p) {
    const int e = p * 256 + lane * 4;
    floatx4 wv = *(const floatx4*)(w + e);
    floatx4 bv = *(const floatx4*)(b + e);
    short4v o;
#pragma unroll
    for (int j = 0; j < 4; ++j) {
      float y = (v[p * 4 + j] - mean) * rstd * wv[j] + bv[j];
      o[j] = (short)f2bf(y);
    }
    *(short4v*)(out + base + e) = o;
  }
}

// ---------------- GEMM: C[M,N] = A[M,K] * B[N,K]^T (+epilogue) ----------------
// 128x128 tile, BK=32, 4 waves (2x2), mfma_f32_16x16x32_bf16, global_load_lds staging.
// AMODE: 0 = normal strides lda/ldb
//        1 = row-attn logits addressing: elem(row,kk) = base + z*96 + (kk/96)*196608 + row*768 + (kk%96)
//        2 = split-K row-attn logits: z = h*16+s, head h, K-window [s*384, s*384+384)
// EPI: 1 f32=acc | 2 bf16=gelu(acc+bz) | 3 f32=resf32+acc+bz | 4 bf16=resf32+acc+bz
//      5 f32=resbf16+acc+bz | 6 bf16=resbf16+acc+bz
//      7 bf16 scatter (row-attn PV): n=(r*96+d) -> out[(r*256+m)*768 + z*96 + d]
//      8 bf16 merged-QKV split write: buf=n/768 -> out + buf*12582912 + m*768 + (n%768)
template<int AMODE, int EPI>
__global__ __launch_bounds__(256) void gemm_bt(
    const u16* __restrict__ A, const u16* __restrict__ B,
    const float* __restrict__ bias, const void* __restrict__ res,
    void* __restrict__ out, int K, int lda, int ldb,
    long long aBatch, long long bBatch, long long outBatch, int ldc, float scale) {
  __shared__ u16 lA[128 * 32];
  __shared__ u16 lB[128 * 32];
  const int t = threadIdx.x;
  const int z = blockIdx.z;
  const int m0 = blockIdx.x * 128, n0 = blockIdx.y * 128;
  const u16* Ab;
  const u16* Bb;
  int koff = 0;
  if constexpr (AMODE == 0) { Ab = A + (size_t)z * aBatch; Bb = B + (size_t)z * bBatch; }
  else if constexpr (AMODE == 1) { Ab = A + z * 96; Bb = B + z * 96; }
  else { const int h = z >> 4; Ab = A + h * 96; Bb = B + h * 96; koff = (z & 15) * 384; }

  const int krow = t >> 2;          // 0..63
  const int kcol = (t & 3) << 3;    // 0,8,16,24
  const int wid = t >> 6, lane = t & 63;
  const int wr = wid >> 1, wc = wid & 1;
  const int lrow = lane & 15, lhi = lane >> 4;

  floatx4 acc[4][4];
#pragma unroll
  for (int i = 0; i < 4; ++i)
#pragma unroll
    for (int j = 0; j < 4; ++j) acc[i][j] = (floatx4){0.f, 0.f, 0.f, 0.f};

  for (int k0 = 0; k0 < K; k0 += 32) {
#pragma unroll
    for (int i = 0; i < 2; ++i) {
      const int row = i * 64 + krow;
      const int kk = koff + k0 + kcol;
      const u16 *ga, *gb;
      if constexpr (AMODE == 0) {
        ga = Ab + (size_t)(m0 + row) * lda + kk;
        gb = Bb + (size_t)(n0 + row) * ldb + kk;
      } else {
        const int r = kk / 96, d = kk - r * 96;  // 8|96 so a lane's 8-chunk never crosses r
        ga = Ab + (size_t)r * 196608 + (size_t)(m0 + row) * 768 + d;
        gb = Bb + (size_t)r * 196608 + (size_t)(n0 + row) * 768 + d;
      }
      async_copy16(ga, lA + i * 2048 + wid * 512);
      async_copy16(gb, lB + i * 2048 + wid * 512);
    }
    asm volatile("s_waitcnt vmcnt(0)" ::: "memory");
    __syncthreads();

    short8 af[4], bfr[4];
#pragma unroll
    for (int mi = 0; mi < 4; ++mi)
      af[mi] = *(const short8*)&lA[(wr * 64 + mi * 16 + lrow) * 32 + lhi * 8];
#pragma unroll
    for (int ni = 0; ni < 4; ++ni)
      bfr[ni] = *(const short8*)&lB[(wc * 64 + ni * 16 + lrow) * 32 + lhi * 8];
#pragma unroll
    for (int mi = 0; mi < 4; ++mi)
#pragma unroll
      for (int ni = 0; ni < 4; ++ni)
        acc[mi][ni] = __builtin_amdgcn_mfma_f32_16x16x32_bf16(af[mi], bfr[ni], acc[mi][ni], 0, 0, 0);
    __syncthreads();
  }

  const int mbase = m0 + wr * 64;
  const int nbase = n0 + wc * 64;
#pragma unroll
  for (int mi = 0; mi < 4; ++mi) {
#pragma unroll
    for (int ni = 0; ni < 4; ++ni) {
      const int n = nbase + ni * 16 + lrow;
      float bz = 0.f;
      if constexpr (EPI != 1 && EPI != 7) { if (bias) bz = bias[n]; }
#pragma unroll
      for (int r4 = 0; r4 < 4; ++r4) {
        const int m = mbase + mi * 16 + lhi * 4 + r4;
        const float val = acc[mi][ni][r4];
        if constexpr (EPI == 1) {
          ((float*)out)[(size_t)z * outBatch + (size_t)m * ldc + n] = val;
        } else if constexpr (EPI == 2) {
          ((u16*)out)[(size_t)m * ldc + n] = f2bf(fast_gelu(val + bz));
        } else if constexpr (EPI == 3) {
          const float r = ((const float*)res)[(size_t)m * ldc + n];
          ((float*)out)[(size_t)m * ldc + n] = r + val + bz;
        } else if constexpr (EPI == 4) {
          const float r = ((const float*)res)[(size_t)m * ldc + n];
          ((u16*)out)[(size_t)m * ldc + n] = f2bf(r + val + bz);
        } else if constexpr (EPI == 5) {
          const float r = bf2f(((const u16*)res)[(size_t)m * ldc + n]);
          ((float*)out)[(size_t)m * ldc + n] = r + val + bz;
        } else if constexpr (EPI == 6) {
          const float r = bf2f(((const u16*)res)[(size_t)m * ldc + n]);
          ((u16*)out)[(size_t)m * ldc + n] = f2bf(r + val + bz);
        } else if constexpr (EPI == 7) {
          const int rr = n / 96, d = n - rr * 96;
          ((u16*)out)[((size_t)(rr * 256 + m)) * 768 + (size_t)z * 96 + d] = f2bf(val);
        } else if constexpr (EPI == 8) {
          const int buf = n / 768, col = n - buf * 768;
          ((u16*)out)[(size_t)buf * 12582912 + (size_t)m * 768 + col] = f2bf(val + bz);
        }
      }
    }
  }
}

// ---------------- row softmax fused with split-K reduce ----------------
// part[(h*16+s)*65536 + i*256 + j]; row = h*256+i; 2048 rows, one wave per row.
__global__ __launch_bounds__(256) void softmax_row(const float* __restrict__ part,
                                                   float* __restrict__ probs_f,
                                                   u16* __restrict__ probs_b) {
  const int wid = threadIdx.x >> 6, lane = threadIdx.x & 63;
  const int row = blockIdx.x * 4 + wid;
  const int h = row >> 8, i = row & 255;
  const size_t base = (size_t)h * 16 * 65536 + (size_t)i * 256 + lane * 4;
  floatx4 v = (floatx4){0.f, 0.f, 0.f, 0.f};
#pragma unroll
  for (int s16 = 0; s16 < 16; ++s16) {
    floatx4 p = *(const floatx4*)(part + base + (size_t)s16 * 65536);
#pragma unroll
    for (int j = 0; j < 4; ++j) v[j] += p[j];
  }
  float mx = fmaxf(fmaxf(v[0], v[1]), fmaxf(v[2], v[3]));
#pragma unroll
  for (int m = 1; m < 64; m <<= 1) mx = fmaxf(mx, __shfl_xor(mx, m));
  float e[4], s = 0.f;
#pragma unroll
  for (int j = 0; j < 4; ++j) { e[j] = __expf(v[j] - mx); s += e[j]; }
#pragma unroll
  for (int m = 1; m < 64; m <<= 1) s += __shfl_xor(s, m);
  const float inv = 1.f / s;
  floatx4 of;
  short4v ob;
#pragma unroll
  for (int j = 0; j < 4; ++j) {
    const float p = e[j] * inv;
    of[j] = p;
    ob[j] = (short)f2bf(p);
  }
  *(floatx4*)(probs_f + (size_t)row * 256 + lane * 4) = of;
  *(short4v*)(probs_b + (size_t)row * 256 + lane * 4) = ob;
}

// ---------------- pack V^T for row-attn PV: vt[h][(r*96+d)][j] = v[(r*256+j)*768+h*96+d]
__global__ __launch_bounds__(256) void pack_vt(const u16* __restrict__ v, u16* __restrict__ vt) {
  __shared__ u16 S[64][104];  // [j][d], padded
  const int jb = blockIdx.x, r = blockIdx.y, h = blockIdx.z;
  const int t = threadIdx.x;
#pragma unroll
  for (int p = 0; p < 3; ++p) {
    const int cid = t + p * 256;
    const int j = cid / 12, ch = cid - j * 12;
    short8 x = *(const short8*)&v[((size_t)(r * 256 + jb * 64 + j)) * 768 + h * 96 + ch * 8];
    *(short8*)&S[j][ch * 8] = x;
  }
  __syncthreads();
#pragma unroll
  for (int p = 0; p < 3; ++p) {
    const int cid = t + p * 256;
    const int d = cid / 8, cj = cid - d * 8;
    u16 tmp[8];
#pragma unroll
    for (int m = 0; m < 8; ++m) tmp[m] = S[cj * 8 + m][d];
    *(short8*)&vt[((size_t)(h * 6144 + r * 96 + d)) * 256 + jb * 64 + cj * 8] = *(short8*)tmp;
  }
}

// ---------------- fused column attention: one block per (c, h) ----------------
__global__ __launch_bounds__(256) void col_attn(const u16* __restrict__ q,
                                                const u16* __restrict__ k,
                                                const u16* __restrict__ v,
                                                float* __restrict__ probs,
                                                u16* __restrict__ ctx) {
  __shared__ u16 qs[64][104];
  __shared__ u16 ks[64][104];
  __shared__ u16 vt[96][72];
  __shared__ u16 ps[64][72];
  const int c = blockIdx.x, h = blockIdx.y;
  const int t = threadIdx.x;
#pragma unroll
  for (int p = 0; p < 3; ++p) {
    const int cid = t + p * 256;
    const int i = cid / 12, ch = cid - i * 12;
    const size_t g = ((size_t)(i * 256 + c)) * 768 + h * 96 + ch * 8;
    short8 qv = *(const short8*)(q + g);
    short8 kv = *(const short8*)(k + g);
    short8 vv = *(const short8*)(v + g);
    *(short8*)&qs[i][ch * 8] = qv;
    *(short8*)&ks[i][ch * 8] = kv;
#pragma unroll
    for (int m = 0; m < 8; ++m) vt[ch * 8 + m][i] = (u16)vv[m];
  }
  __syncthreads();
  const int lane = t & 63, wid = t >> 6;
  const int lrow = lane & 15, lhi = lane >> 4;

  floatx4 s[4];
#pragma unroll
  for (int nj = 0; nj < 4; ++nj) s[nj] = (floatx4){0.f, 0.f, 0.f, 0.f};
#pragma unroll
  for (int kk = 0; kk < 3; ++kk) {
    short8 a = *(const short8*)&qs[wid * 16 + lrow][kk * 32 + lhi * 8];
#pragma unroll
    for (int nj = 0; nj < 4; ++nj) {
      short8 bb = *(const short8*)&ks[nj * 16 + lrow][kk * 32 + lhi * 8];
      s[nj] = __builtin_amdgcn_mfma_f32_16x16x32_bf16(a, bb, s[nj], 0, 0, 0);
    }
  }
  const size_t pb = ((size_t)(h * 256 + c)) * 4096;
#pragma unroll
  for (int r4 = 0; r4 < 4; ++r4) {
    float mx = fmaxf(fmaxf(s[0][r4], s[1][r4]), fmaxf(s[2][r4], s[3][r4]));
    mx = fmaxf(mx, __shfl_xor(mx, 1));
    mx = fmaxf(mx, __shfl_xor(mx, 2));
    mx = fmaxf(mx, __shfl_xor(mx, 4));
    mx = fmaxf(mx, __shfl_xor(mx, 8));
    float e[4], sum = 0.f;
#pragma unroll
    for (int nj = 0; nj < 4; ++nj) { e[nj] = __expf(s[nj][r4] - mx); sum += e[nj]; }
    sum += __shfl_xor(sum, 1);
    sum += __shfl_xor(sum, 2);
    sum += __shfl_xor(sum, 4);
    sum += __shfl_xor(sum, 8);
    const float inv = 1.f / sum;
    const int i = wid * 16 + lhi * 4 + r4;
#pragma unroll
    for (int nj = 0; nj < 4; ++nj) {
      const float pv = e[nj] * inv;
      const int j = nj * 16 + lrow;
      probs[pb + (size_t)i * 64 + j] = pv;
      ps[i][j] = f2bf(pv);
    }
  }
  __syncthreads();
  floatx4 o[6];
#pragma unroll
  for (int df = 0; df < 6; ++df) o[df] = (floatx4){0.f, 0.f, 0.f, 0.f};
#pragma unroll
  for (int k2 = 0; k2 < 2; ++k2) {
    short8 a = *(const short8*)&ps[wid * 16 + lrow][k2 * 32 + lhi * 8];
#pragma unroll
    for (int df = 0; df < 6; ++df) {
      short8 bb = *(const short8*)&vt[df * 16 + lrow][k2 * 32 + lhi * 8];
      o[df] = __builtin_amdgcn_mfma_f32_16x16x32_bf16(a, bb, o[df], 0, 0, 0);
    }
  }
#pragma unroll
  for (int df = 0; df < 6; ++df)
#pragma unroll
    for (int r4 = 0; r4 < 4; ++r4) {
      const int i = wid * 16 + lhi * 4 + r4;
      const int d = df * 16 + lrow;
      ctx[((size_t)(i * 256 + c)) * 768 + h * 96 + d] = f2bf(o[df][r4]);
    }
}

// ---------------- host launch ----------------
extern "C" void kernel_launch(void* const* d_in, const int* in_sizes, int n_in,
                              void* d_out, int out_size, void* d_ws, size_t ws_size,
                              hipStream_t stream) {
  const float* x_in  = (const float*)d_in[0];
  const float* lnr_w = (const float*)d_in[1];
  const float* lnr_b = (const float*)d_in[2];
  const float* rq_w  = (const float*)d_in[3];
  const float* rq_b  = (const float*)d_in[4];
  const float* rk_w  = (const float*)d_in[5];
  const float* rk_b  = (const float*)d_in[6];
  const float* rv_w  = (const float*)d_in[7];
  const float* rv_b  = (const float*)d_in[8];
  const float* ro_w  = (const float*)d_in[9];
  const float* ro_b  = (const float*)d_in[10];
  const float* lnc_w = (const float*)d_in[11];
  const float* lnc_b = (const float*)d_in[12];
  const float* cq_w  = (const float*)d_in[13];
  const float* cq_b  = (const float*)d_in[14];
  const float* ck_w  = (const float*)d_in[15];
  const float* ck_b  = (const float*)d_in[16];
  const float* cv_w  = (const float*)d_in[17];
  const float* cv_b  = (const float*)d_in[18];
  const float* co_w  = (const float*)d_in[19];
  const float* co_b  = (const float*)d_in[20];
  const float* lnf_w = (const float*)d_in[21];
  const float* lnf_b = (const float*)d_in[22];
  const float* f1_w  = (const float*)d_in[23];
  const float* f1_b  = (const float*)d_in[24];
  const float* f2_w  = (const float*)d_in[25];
  const float* f2_b  = (const float*)d_in[26];

  const float s_row = 0.0127577591f;  // (96^-0.5)/8
  const float s_col = 0.1020620726f;  // 96^-0.5

  // ---- ws layout ----
  char* ws = (char*)d_ws;
  const size_t WSZ_E = 589824 * 2;        // one E x E bf16 weight
  u16* w_all = (u16*)ws;                  // rq,rk,rv | ro | cq,ck,cv | co | f1 | f2
  u16* w_rqkv = w_all;
  u16* w_ro   = (u16*)(ws + 3 * WSZ_E);
  u16* w_cqkv = (u16*)(ws + 4 * WSZ_E);
  u16* w_co   = (u16*)(ws + 7 * WSZ_E);
  u16* w_f1   = (u16*)(ws + 8 * WSZ_E);                 // 4,718,592 B
  u16* w_f2   = (u16*)(ws + 8 * WSZ_E + 4718592);       // 4,718,592 B
  size_t off = 8 * WSZ_E + 2 * 4718592;                 // 18,874,368

  const bool xf32 = ws_size >= 147849216ULL;            // f32 residual if it fits
  char* x_cur = ws + off;                               // f32 (50.3MB) or bf16 (25.2MB)
  off += xf32 ? 50331648 : 25165824;
  u16* qb = (u16*)(ws + off); off += 25165824;
  u16* kb = (u16*)(ws + off); off += 25165824;
  u16* vb = (u16*)(ws + off); off += 25165824;
  u16* probsb = (u16*)(ws + off); off += 1048576;       // bf16 row probs
  float* qkvb_row = (float*)(ws + off); off += 9216;    // [2304] f32
  float* qkvb_col = (float*)(ws + off); off += 9216;

  u16* vt     = qb;            // row-attn V^T overlays qb (free after logits)
  u16* ctx1   = kb;            // row-attn context overlays kb
  u16* hidden = qb;            // FFN hidden chunk (50.3MB) overlays qb+kb
  u16* xn3    = vb;            // stage-3 LN output overlays vb

  // ---- d_out layout + d_out-as-scratch ----
  float* out_x  = (float*)d_out;            // 12,582,912 f32 (free until final fc2)
  float* out_rp = out_x + 12582912;         // row_probs [8,1,256,256] f32
  float* out_cp = out_x + 13107200;         // col_probs [8,256,1,64,64] f32
  u16* xn   = (u16*)out_x;                  // LN out (stages 1,2), lower half of out_x
  u16* ctx2 = (u16*)((char*)out_x + 25165824);  // col-attn context, upper half
  float* part = out_x;                      // split-K logits partials (33.5MB, dead after softmax)

  const dim3 blk(256);

  // ---- weight conversion (one dispatch) + bias packs ----
  CvtArgs ca;
  ca.src[0] = rq_w; ca.src[1] = rk_w; ca.src[2] = rv_w; ca.src[3] = ro_w;
  ca.src[4] = cq_w; ca.src[5] = ck_w; ca.src[6] = cv_w; ca.src[7] = co_w;
  ca.src[8] = f1_w; ca.src[9] = f2_w;
  for (int i = 0; i < 10; ++i) ca.scale[i] = 1.f;
  ca.scale[0] = s_row; ca.scale[4] = s_col;
  cvt_all<<<9216, blk, 0, stream>>>(ca, w_all);
  bias_pack<<<9, blk, 0, stream>>>(rq_b, rk_b, rv_b, s_row, qkvb_row);
  bias_pack<<<9, blk, 0, stream>>>(cq_b, ck_b, cv_b, s_col, qkvb_col);

  // ---- Stage 1: row attention ----
  ln_kernel<true><<<4096, blk, 0, stream>>>(x_in, lnr_w, lnr_b, xn);
  gemm_bt<0, 8><<<dim3(128, 18, 1), blk, 0, stream>>>(xn, w_rqkv, qkvb_row, nullptr, qb, 768, 768, 768, 0, 0, 0, 768, 1.f);
  // split-K logits: grid.z = h*16+s, partials into d_out scratch (xn is dead now)
  gemm_bt<2, 1><<<dim3(2, 2, 128), blk, 0, stream>>>(qb, kb, nullptr, nullptr, part, 384, 0, 0, 0, 0, 65536LL, 256, 1.f);
  softmax_row<<<512, blk, 0, stream>>>(part, out_rp, probsb);
  pack_vt<<<dim3(4, 64, 8), blk, 0, stream>>>(vb, vt);
  gemm_bt<0, 7><<<dim3(2, 48, 8), blk, 0, stream>>>(probsb, vt, nullptr, nullptr, ctx1, 256, 256, 256, 65536LL, 1572864LL, 0, 0, 1.f);
  if (xf32)
    gemm_bt<0, 3><<<dim3(128, 6, 1), blk, 0, stream>>>(ctx1, w_ro, ro_b, x_in, x_cur, 768, 768, 768, 0, 0, 0, 768, 1.f);
  else
    gemm_bt<0, 4><<<dim3(128, 6, 1), blk, 0, stream>>>(ctx1, w_ro, ro_b, x_in, x_cur, 768, 768, 768, 0, 0, 0, 768, 1.f);

  // ---- Stage 2: column attention ----
  if (xf32) ln_kernel<true><<<4096, blk, 0, stream>>>(x_cur, lnc_w, lnc_b, xn);
  else      ln_kernel<false><<<4096, blk, 0, stream>>>(x_cur, lnc_w, lnc_b, xn);
  gemm_bt<0, 8><<<dim3(128, 18, 1), blk, 0, stream>>>(xn, w_cqkv, qkvb_col, nullptr, qb, 768, 768, 768, 0, 0, 0, 768, 1.f);
  col_attn<<<dim3(256, 8), blk, 0, stream>>>(qb, kb, vb, out_cp, ctx2);
  if (xf32)
    gemm_bt<0, 3><<<dim3(128, 6, 1), blk, 0, stream>>>(ctx2, w_co, co_b, x_cur, x_cur, 768, 768, 768, 0, 0, 0, 768, 1.f);
  else
    gemm_bt<0, 6><<<dim3(128, 6, 1), blk, 0, stream>>>(ctx2, w_co, co_b, x_cur, x_cur, 768, 768, 768, 0, 0, 0, 768, 1.f);

  // ---- Stage 3: FFN (F chunked 2x1536 so hidden fits qb+kb) ----
  if (xf32) ln_kernel<true><<<4096, blk, 0, stream>>>(x_cur, lnf_w, lnf_b, xn3);
  else      ln_kernel<false><<<4096, blk, 0, stream>>>(x_cur, lnf_w, lnf_b, xn3);
  // chunk 0
  gemm_bt<0, 2><<<dim3(128, 12, 1), blk, 0, stream>>>(xn3, w_f1, f1_b, nullptr, hidden, 768, 768, 768, 0, 0, 0, 1536, 1.f);
  if (xf32)
    gemm_bt<0, 3><<<dim3(128, 6, 1), blk, 0, stream>>>(hidden, w_f2, f2_b, x_cur, out_x, 1536, 1536, 3072, 0, 0, 0, 768, 1.f);
  else
    gemm_bt<0, 5><<<dim3(128, 6, 1), blk, 0, stream>>>(hidden, w_f2, f2_b, x_cur, out_x, 1536, 1536, 3072, 0, 0, 0, 768, 1.f);
  // chunk 1 (accumulate into out_x)
  gemm_bt<0, 2><<<dim3(128, 12, 1), blk, 0, stream>>>(xn3, w_f1 + 1536 * 768, f1_b + 1536, nullptr, hidden, 768, 768, 768, 0, 0, 0, 1536, 1.f);
  gemm_bt<0, 3><<<dim3(128, 6, 1), blk, 0, stream>>>(hidden, w_f2 + 1536, nullptr, out_x, out_x, 1536, 1536, 3072, 0, 0, 0, 768, 1.f);
}

// Round 7
// 660.618 us; speedup vs baseline: 1.2542x; 1.0030x over previous
//
#include <hip/hip_runtime.h>
#include <cstdint>

typedef unsigned short u16;
typedef __attribute__((ext_vector_type(8))) short short8;   // 8 x bf16 (4 VGPR)
typedef __attribute__((ext_vector_type(4))) short short4v;  // 4 x bf16
typedef __attribute__((ext_vector_type(4))) float floatx4;  // MFMA acc / float4

#define DEV __device__ __forceinline__

DEV float bf2f(u16 u) { union { uint32_t i; float f; } w; w.i = ((uint32_t)u) << 16; return w.f; }
DEV u16 f2bf(float f) {
  union { float f; uint32_t i; } w; w.f = f;
  uint32_t x = w.i;
  return (u16)((x + 0x7fffu + ((x >> 16) & 1u)) >> 16);  // RNE
}

// fast exact-gelu: A&S 7.1.26 erf approx, |err|<=1.5e-7, branchless
DEV float fast_gelu(float x) {
  const float y = x * 0.70710678118f;
  const float ay = fabsf(y);
  const float t = 1.f / (1.f + 0.3275911f * ay);
  const float poly = t * (0.254829592f + t * (-0.284496736f +
                     t * (1.421413741f + t * (-1.453152027f + t * 1.061405429f))));
  const float er = 1.f - poly * __expf(-y * y);
  const float erf_y = __builtin_copysignf(er, y);
  return 0.5f * x * (1.f + erf_y);
}

// async global->LDS, 16B per lane. LDS dest must be wave-uniform base; HW adds lane*16.
DEV void async_copy16(const u16* g, u16* l) {
  __builtin_amdgcn_global_load_lds(
      (const __attribute__((address_space(1))) void*)(uintptr_t)g,
      (__attribute__((address_space(3))) void*)(uint32_t)(uintptr_t)l,
      16, 0, 0);
}

// ---------------- fused f32 -> bf16 weight convert (all 10 weights) ----------------
// dst layout (contiguous): rq,rk,rv,ro,cq,ck,cv,co (589824 each), f1,f2 (2359296 each)
struct CvtArgs {
  const float* src[10];
  float scale[10];
};
__global__ __launch_bounds__(256) void cvt_all(CvtArgs a, u16* __restrict__ dst) {
  const size_t e = ((size_t)blockIdx.x * 256 + threadIdx.x) * 4;  // 9437184 total elems
  if (e >= 9437184) return;
  int reg;
  size_t base;
  if (e < 4718592) { reg = (int)(e / 589824); base = (size_t)reg * 589824; }
  else if (e < 7077888) { reg = 8; base = 4718592; }
  else { reg = 9; base = 7077888; }
  const float sc = a.scale[reg];
  floatx4 f = *(const floatx4*)(a.src[reg] + (e - base));
  short4v o;
#pragma unroll
  for (int j = 0; j < 4; ++j) o[j] = (short)f2bf(f[j] * sc);
  *(short4v*)(dst + e) = o;
}

// pack q/k/v biases into one [2304] f32 buffer per stage, q part pre-scaled
__global__ __launch_bounds__(256) void bias_pack(const float* __restrict__ qb,
                                                 const float* __restrict__ kb,
                                                 const float* __restrict__ vb,
                                                 float sq, float* __restrict__ out) {
  const int i = blockIdx.x * 256 + threadIdx.x;
  if (i >= 2304) return;
  const int buf = i / 768, c = i - buf * 768;
  out[i] = buf == 0 ? qb[c] * sq : (buf == 1 ? kb[c] : vb[c]);
}

// ---------------- LayerNorm: one wave per row of 768, bf16 out ----------------
template<bool INF32>
__global__ __launch_bounds__(256) void ln_kernel(const void* __restrict__ in,
                                                 const float* __restrict__ w,
                                                 const float* __restrict__ b,
                                                 u16* __restrict__ out) {
  const int wid = threadIdx.x >> 6, lane = threadIdx.x & 63;
  const int row = blockIdx.x * 4 + wid;  // 16384 rows
  const size_t base = (size_t)row * 768;
  float v[12];
#pragma unroll
  for (int p = 0; p < 3; ++p) {
    const int e = p * 256 + lane * 4;
    if constexpr (INF32) {
      floatx4 f = *(const floatx4*)((const float*)in + base + e);
#pragma unroll
      for (int j = 0; j < 4; ++j) v[p * 4 + j] = f[j];
    } else {
      short4v u = *(const short4v*)((const u16*)in + base + e);
#pragma unroll
      for (int j = 0; j < 4; ++j) v[p * 4 + j] = bf2f((u16)u[j]);
    }
  }
  float s = 0.f, sq = 0.f;
#pragma unroll
  for (int i = 0; i < 12; ++i) { s += v[i]; sq += v[i] * v[i]; }
#pragma unroll
  for (int m = 1; m < 64; m <<= 1) { s += __shfl_xor(s, m); sq += __shfl_xor(sq, m); }
  const float mean = s * (1.f / 768.f);
  const float var = sq * (1.f / 768.f) - mean * mean;
  const float rstd = rsqrtf(var + 1e-5f);
#pragma unroll
  for (int p = 0; p < 3; ++p) {
    const int e = p * 256 + lane * 4;
    floatx4 wv = *(const floatx4*)(w + e);
    floatx4 bv = *(const floatx4*)(b + e);
    short4v o;
#pragma unroll
    for (int j = 0; j < 4; ++j) {
      float y = (v[p * 4 + j] - mean) * rstd * wv[j] + bv[j];
      o[j] = (short)f2bf(y);
    }
    *(short4v*)(out + base + e) = o;
  }
}

// ---------------- GEMM: C[M,N] = A[M,K] * B[N,K]^T (+epilogue) ----------------
// 128x128 tile, BK=32, 4 waves (2x2), mfma_f32_16x16x32_bf16, global_load_lds staging.
// AMODE: 0 = normal strides lda/ldb
//        1 = row-attn logits addressing: elem(row,kk) = base + z*96 + (kk/96)*196608 + row*768 + (kk%96)
//        2 = split-K row-attn logits: z = h*16+s, head h, K-window [s*384, s*384+384)
// EPI: 1 f32=acc | 2 bf16=gelu(acc+bz) | 3 f32=resf32+acc+bz | 4 bf16=resf32+acc+bz
//      5 f32=resbf16+acc+bz | 6 bf16=resbf16+acc+bz
//      7 bf16 scatter (row-attn PV): n=(r*96+d) -> out[(r*256+m)*768 + z*96 + d]
//      8 bf16 merged-QKV split write: buf=n/768 -> out + buf*12582912 + m*768 + (n%768)
template<int AMODE, int EPI>
__global__ __launch_bounds__(256) void gemm_bt(
    const u16* __restrict__ A, const u16* __restrict__ B,
    const float* __restrict__ bias, const void* __restrict__ res,
    void* __restrict__ out, int K, int lda, int ldb,
    long long aBatch, long long bBatch, long long outBatch, int ldc, float scale) {
  __shared__ u16 lA[128 * 32];
  __shared__ u16 lB[128 * 32];
  const int t = threadIdx.x;
  const int z = blockIdx.z;
  const int m0 = blockIdx.x * 128, n0 = blockIdx.y * 128;
  const u16* Ab;
  const u16* Bb;
  int koff = 0;
  if constexpr (AMODE == 0) { Ab = A + (size_t)z * aBatch; Bb = B + (size_t)z * bBatch; }
  else if constexpr (AMODE == 1) { Ab = A + z * 96; Bb = B + z * 96; }
  else { const int h = z >> 4; Ab = A + h * 96; Bb = B + h * 96; koff = (z & 15) * 384; }

  const int krow = t >> 2;          // 0..63
  const int kcol = (t & 3) << 3;    // 0,8,16,24
  const int wid = t >> 6, lane = t & 63;
  const int wr = wid >> 1, wc = wid & 1;
  const int lrow = lane & 15, lhi = lane >> 4;

  floatx4 acc[4][4];
#pragma unroll
  for (int i = 0; i < 4; ++i)
#pragma unroll
    for (int j = 0; j < 4; ++j) acc[i][j] = (floatx4){0.f, 0.f, 0.f, 0.f};

  for (int k0 = 0; k0 < K; k0 += 32) {
#pragma unroll
    for (int i = 0; i < 2; ++i) {
      const int row = i * 64 + krow;
      const int kk = koff + k0 + kcol;
      const u16 *ga, *gb;
      if constexpr (AMODE == 0) {
        ga = Ab + (size_t)(m0 + row) * lda + kk;
        gb = Bb + (size_t)(n0 + row) * ldb + kk;
      } else {
        const int r = kk / 96, d = kk - r * 96;  // 8|96 so a lane's 8-chunk never crosses r
        ga = Ab + (size_t)r * 196608 + (size_t)(m0 + row) * 768 + d;
        gb = Bb + (size_t)r * 196608 + (size_t)(n0 + row) * 768 + d;
      }
      async_copy16(ga, lA + i * 2048 + wid * 512);
      async_copy16(gb, lB + i * 2048 + wid * 512);
    }
    asm volatile("s_waitcnt vmcnt(0)" ::: "memory");
    __syncthreads();

    short8 af[4], bfr[4];
#pragma unroll
    for (int mi = 0; mi < 4; ++mi)
      af[mi] = *(const short8*)&lA[(wr * 64 + mi * 16 + lrow) * 32 + lhi * 8];
#pragma unroll
    for (int ni = 0; ni < 4; ++ni)
      bfr[ni] = *(const short8*)&lB[(wc * 64 + ni * 16 + lrow) * 32 + lhi * 8];
#pragma unroll
    for (int mi = 0; mi < 4; ++mi)
#pragma unroll
      for (int ni = 0; ni < 4; ++ni)
        acc[mi][ni] = __builtin_amdgcn_mfma_f32_16x16x32_bf16(af[mi], bfr[ni], acc[mi][ni], 0, 0, 0);
    __syncthreads();
  }

  const int mbase = m0 + wr * 64;
  const int nbase = n0 + wc * 64;
#pragma unroll
  for (int mi = 0; mi < 4; ++mi) {
#pragma unroll
    for (int ni = 0; ni < 4; ++ni) {
      const int n = nbase + ni * 16 + lrow;
      float bz = 0.f;
      if constexpr (EPI != 1 && EPI != 7) { if (bias) bz = bias[n]; }
#pragma unroll
      for (int r4 = 0; r4 < 4; ++r4) {
        const int m = mbase + mi * 16 + lhi * 4 + r4;
        const float val = acc[mi][ni][r4];
        if constexpr (EPI == 1) {
          ((float*)out)[(size_t)z * outBatch + (size_t)m * ldc + n] = val;
        } else if constexpr (EPI == 2) {
          ((u16*)out)[(size_t)m * ldc + n] = f2bf(fast_gelu(val + bz));
        } else if constexpr (EPI == 3) {
          const float r = ((const float*)res)[(size_t)m * ldc + n];
          ((float*)out)[(size_t)m * ldc + n] = r + val + bz;
        } else if constexpr (EPI == 4) {
          const float r = ((const float*)res)[(size_t)m * ldc + n];
          ((u16*)out)[(size_t)m * ldc + n] = f2bf(r + val + bz);
        } else if constexpr (EPI == 5) {
          const float r = bf2f(((const u16*)res)[(size_t)m * ldc + n]);
          ((float*)out)[(size_t)m * ldc + n] = r + val + bz;
        } else if constexpr (EPI == 6) {
          const float r = bf2f(((const u16*)res)[(size_t)m * ldc + n]);
          ((u16*)out)[(size_t)m * ldc + n] = f2bf(r + val + bz);
        } else if constexpr (EPI == 7) {
          const int rr = n / 96, d = n - rr * 96;
          ((u16*)out)[((size_t)(rr * 256 + m)) * 768 + (size_t)z * 96 + d] = f2bf(val);
        } else if constexpr (EPI == 8) {
          const int buf = n / 768, col = n - buf * 768;
          ((u16*)out)[(size_t)buf * 12582912 + (size_t)m * 768 + col] = f2bf(val + bz);
        }
      }
    }
  }
}

// ---------------- row softmax fused with split-K reduce ----------------
// part[(h*16+s)*65536 + i*256 + j]; row = h*256+i; 2048 rows, one wave per row.
__global__ __launch_bounds__(256) void softmax_row(const float* __restrict__ part,
                                                   float* __restrict__ probs_f,
                                                   u16* __restrict__ probs_b) {
  const int wid = threadIdx.x >> 6, lane = threadIdx.x & 63;
  const int row = blockIdx.x * 4 + wid;
  const int h = row >> 8, i = row & 255;
  const size_t base = (size_t)h * 16 * 65536 + (size_t)i * 256 + lane * 4;
  floatx4 v = (floatx4){0.f, 0.f, 0.f, 0.f};
#pragma unroll
  for (int s16 = 0; s16 < 16; ++s16) {
    floatx4 p = *(const floatx4*)(part + base + (size_t)s16 * 65536);
#pragma unroll
    for (int j = 0; j < 4; ++j) v[j] += p[j];
  }
  float mx = fmaxf(fmaxf(v[0], v[1]), fmaxf(v[2], v[3]));
#pragma unroll
  for (int m = 1; m < 64; m <<= 1) mx = fmaxf(mx, __shfl_xor(mx, m));
  float e[4], s = 0.f;
#pragma unroll
  for (int j = 0; j < 4; ++j) { e[j] = __expf(v[j] - mx); s += e[j]; }
#pragma unroll
  for (int m = 1; m < 64; m <<= 1) s += __shfl_xor(s, m);
  const float inv = 1.f / s;
  floatx4 of;
  short4v ob;
#pragma unroll
  for (int j = 0; j < 4; ++j) {
    const float p = e[j] * inv;
    of[j] = p;
    ob[j] = (short)f2bf(p);
  }
  *(floatx4*)(probs_f + (size_t)row * 256 + lane * 4) = of;
  *(short4v*)(probs_b + (size_t)row * 256 + lane * 4) = ob;
}

// ---------------- pack V^T for row-attn PV: vt[h][(r*96+d)][j] = v[(r*256+j)*768+h*96+d]
__global__ __launch_bounds__(256) void pack_vt(const u16* __restrict__ v, u16* __restrict__ vt) {
  __shared__ u16 S[64][104];  // [j][d], padded
  const int jb = blockIdx.x, r = blockIdx.y, h = blockIdx.z;
  const int t = threadIdx.x;
#pragma unroll
  for (int p = 0; p < 3; ++p) {
    const int cid = t + p * 256;
    const int j = cid / 12, ch = cid - j * 12;
    short8 x = *(const short8*)&v[((size_t)(r * 256 + jb * 64 + j)) * 768 + h * 96 + ch * 8];
    *(short8*)&S[j][ch * 8] = x;
  }
  __syncthreads();
#pragma unroll
  for (int p = 0; p < 3; ++p) {
    const int cid = t + p * 256;
    const int d = cid / 8, cj = cid - d * 8;
    u16 tmp[8];
#pragma unroll
    for (int m = 0; m < 8; ++m) tmp[m] = S[cj * 8 + m][d];
    *(short8*)&vt[((size_t)(h * 6144 + r * 96 + d)) * 256 + jb * 64 + cj * 8] = *(short8*)tmp;
  }
}

// ---------------- fused column attention: one block per (c, h) ----------------
__global__ __launch_bounds__(256) void col_attn(const u16* __restrict__ q,
                                                const u16* __restrict__ k,
                                                const u16* __restrict__ v,
                                                float* __restrict__ probs,
                                                u16* __restrict__ ctx) {
  __shared__ u16 qs[64][104];
  __shared__ u16 ks[64][104];
  __shared__ u16 vt[96][72];
  __shared__ u16 ps[64][72];
  const int c = blockIdx.x, h = blockIdx.y;
  const int t = threadIdx.x;
#pragma unroll
  for (int p = 0; p < 3; ++p) {
    const int cid = t + p * 256;
    const int i = cid / 12, ch = cid - i * 12;
    const size_t g = ((size_t)(i * 256 + c)) * 768 + h * 96 + ch * 8;
    short8 qv = *(const short8*)(q + g);
    short8 kv = *(const short8*)(k + g);
    short8 vv = *(const short8*)(v + g);
    *(short8*)&qs[i][ch * 8] = qv;
    *(short8*)&ks[i][ch * 8] = kv;
#pragma unroll
    for (int m = 0; m < 8; ++m) vt[ch * 8 + m][i] = (u16)vv[m];
  }
  __syncthreads();
  const int lane = t & 63, wid = t >> 6;
  const int lrow = lane & 15, lhi = lane >> 4;

  floatx4 s[4];
#pragma unroll
  for (int nj = 0; nj < 4; ++nj) s[nj] = (floatx4){0.f, 0.f, 0.f, 0.f};
#pragma unroll
  for (int kk = 0; kk < 3; ++kk) {
    short8 a = *(const short8*)&qs[wid * 16 + lrow][kk * 32 + lhi * 8];
#pragma unroll
    for (int nj = 0; nj < 4; ++nj) {
      short8 bb = *(const short8*)&ks[nj * 16 + lrow][kk * 32 + lhi * 8];
      s[nj] = __builtin_amdgcn_mfma_f32_16x16x32_bf16(a, bb, s[nj], 0, 0, 0);
    }
  }
  const size_t pb = ((size_t)(h * 256 + c)) * 4096;
#pragma unroll
  for (int r4 = 0; r4 < 4; ++r4) {
    float mx = fmaxf(fmaxf(s[0][r4], s[1][r4]), fmaxf(s[2][r4], s[3][r4]));
    mx = fmaxf(mx, __shfl_xor(mx, 1));
    mx = fmaxf(mx, __shfl_xor(mx, 2));
    mx = fmaxf(mx, __shfl_xor(mx, 4));
    mx = fmaxf(mx, __shfl_xor(mx, 8));
    float e[4], sum = 0.f;
#pragma unroll
    for (int nj = 0; nj < 4; ++nj) { e[nj] = __expf(s[nj][r4] - mx); sum += e[nj]; }
    sum += __shfl_xor(sum, 1);
    sum += __shfl_xor(sum, 2);
    sum += __shfl_xor(sum, 4);
    sum += __shfl_xor(sum, 8);
    const float inv = 1.f / sum;
    const int i = wid * 16 + lhi * 4 + r4;
#pragma unroll
    for (int nj = 0; nj < 4; ++nj) {
      const float pv = e[nj] * inv;
      const int j = nj * 16 + lrow;
      probs[pb + (size_t)i * 64 + j] = pv;
      ps[i][j] = f2bf(pv);
    }
  }
  __syncthreads();
  floatx4 o[6];
#pragma unroll
  for (int df = 0; df < 6; ++df) o[df] = (floatx4){0.f, 0.f, 0.f, 0.f};
#pragma unroll
  for (int k2 = 0; k2 < 2; ++k2) {
    short8 a = *(const short8*)&ps[wid * 16 + lrow][k2 * 32 + lhi * 8];
#pragma unroll
    for (int df = 0; df < 6; ++df) {
      short8 bb = *(const short8*)&vt[df * 16 + lrow][k2 * 32 + lhi * 8];
      o[df] = __builtin_amdgcn_mfma_f32_16x16x32_bf16(a, bb, o[df], 0, 0, 0);
    }
  }
#pragma unroll
  for (int df = 0; df < 6; ++df)
#pragma unroll
    for (int r4 = 0; r4 < 4; ++r4) {
      const int i = wid * 16 + lhi * 4 + r4;
      const int d = df * 16 + lrow;
      ctx[((size_t)(i * 256 + c)) * 768 + h * 96 + d] = f2bf(o[df][r4]);
    }
}

// ---------------- host launch ----------------
extern "C" void kernel_launch(void* const* d_in, const int* in_sizes, int n_in,
                              void* d_out, int out_size, void* d_ws, size_t ws_size,
                              hipStream_t stream) {
  const float* x_in  = (const float*)d_in[0];
  const float* lnr_w = (const float*)d_in[1];
  const float* lnr_b = (const float*)d_in[2];
  const float* rq_w  = (const float*)d_in[3];
  const float* rq_b  = (const float*)d_in[4];
  const float* rk_w  = (const float*)d_in[5];
  const float* rk_b  = (const float*)d_in[6];
  const float* rv_w  = (const float*)d_in[7];
  const float* rv_b  = (const float*)d_in[8];
  const float* ro_w  = (const float*)d_in[9];
  const float* ro_b  = (const float*)d_in[10];
  const float* lnc_w = (const float*)d_in[11];
  const float* lnc_b = (const float*)d_in[12];
  const float* cq_w  = (const float*)d_in[13];
  const float* cq_b  = (const float*)d_in[14];
  const float* ck_w  = (const float*)d_in[15];
  const float* ck_b  = (const float*)d_in[16];
  const float* cv_w  = (const float*)d_in[17];
  const float* cv_b  = (const float*)d_in[18];
  const float* co_w  = (const float*)d_in[19];
  const float* co_b  = (const float*)d_in[20];
  const float* lnf_w = (const float*)d_in[21];
  const float* lnf_b = (const float*)d_in[22];
  const float* f1_w  = (const float*)d_in[23];
  const float* f1_b  = (const float*)d_in[24];
  const float* f2_w  = (const float*)d_in[25];
  const float* f2_b  = (const float*)d_in[26];

  const float s_row = 0.0127577591f;  // (96^-0.5)/8
  const float s_col = 0.1020620726f;  // 96^-0.5

  // ---- ws layout ----
  char* ws = (char*)d_ws;
  const size_t WSZ_E = 589824 * 2;        // one E x E bf16 weight
  u16* w_all = (u16*)ws;                  // rq,rk,rv | ro | cq,ck,cv | co | f1 | f2
  u16* w_rqkv = w_all;
  u16* w_ro   = (u16*)(ws + 3 * WSZ_E);
  u16* w_cqkv = (u16*)(ws + 4 * WSZ_E);
  u16* w_co   = (u16*)(ws + 7 * WSZ_E);
  u16* w_f1   = (u16*)(ws + 8 * WSZ_E);                 // 4,718,592 B
  u16* w_f2   = (u16*)(ws + 8 * WSZ_E + 4718592);       // 4,718,592 B
  size_t off = 8 * WSZ_E + 2 * 4718592;                 // 18,874,368

  const bool xf32 = ws_size >= 147849216ULL;            // f32 residual if it fits
  char* x_cur = ws + off;                               // f32 (50.3MB) or bf16 (25.2MB)
  off += xf32 ? 50331648 : 25165824;
  u16* qb = (u16*)(ws + off); off += 25165824;
  u16* kb = (u16*)(ws + off); off += 25165824;
  u16* vb = (u16*)(ws + off); off += 25165824;
  u16* probsb = (u16*)(ws + off); off += 1048576;       // bf16 row probs
  float* qkvb_row = (float*)(ws + off); off += 9216;    // [2304] f32
  float* qkvb_col = (float*)(ws + off); off += 9216;

  u16* vt     = qb;            // row-attn V^T overlays qb (free after logits)
  u16* ctx1   = kb;            // row-attn context overlays kb
  u16* hidden = qb;            // FFN hidden chunk (50.3MB) overlays qb+kb
  u16* xn3    = vb;            // stage-3 LN output overlays vb

  // ---- d_out layout + d_out-as-scratch ----
  float* out_x  = (float*)d_out;            // 12,582,912 f32 (free until final fc2)
  float* out_rp = out_x + 12582912;         // row_probs [8,1,256,256] f32
  float* out_cp = out_x + 13107200;         // col_probs [8,256,1,64,64] f32
  u16* xn   = (u16*)out_x;                  // LN out (stages 1,2), lower half of out_x
  u16* ctx2 = (u16*)((char*)out_x + 25165824);  // col-attn context, upper half
  float* part = out_x;                      // split-K logits partials (33.5MB, dead after softmax)

  const dim3 blk(256);

  // ---- weight conversion (one dispatch) + bias packs ----
  CvtArgs ca;
  ca.src[0] = rq_w; ca.src[1] = rk_w; ca.src[2] = rv_w; ca.src[3] = ro_w;
  ca.src[4] = cq_w; ca.src[5] = ck_w; ca.src[6] = cv_w; ca.src[7] = co_w;
  ca.src[8] = f1_w; ca.src[9] = f2_w;
  for (int i = 0; i < 10; ++i) ca.scale[i] = 1.f;
  ca.scale[0] = s_row; ca.scale[4] = s_col;
  cvt_all<<<9216, blk, 0, stream>>>(ca, w_all);
  bias_pack<<<9, blk, 0, stream>>>(rq_b, rk_b, rv_b, s_row, qkvb_row);
  bias_pack<<<9, blk, 0, stream>>>(cq_b, ck_b, cv_b, s_col, qkvb_col);

  // ---- Stage 1: row attention ----
  ln_kernel<true><<<4096, blk, 0, stream>>>(x_in, lnr_w, lnr_b, xn);
  gemm_bt<0, 8><<<dim3(128, 18, 1), blk, 0, stream>>>(xn, w_rqkv, qkvb_row, nullptr, qb, 768, 768, 768, 0, 0, 0, 768, 1.f);
  // split-K logits: grid.z = h*16+s, partials into d_out scratch (xn is dead now)
  gemm_bt<2, 1><<<dim3(2, 2, 128), blk, 0, stream>>>(qb, kb, nullptr, nullptr, part, 384, 0, 0, 0, 0, 65536LL, 256, 1.f);
  softmax_row<<<512, blk, 0, stream>>>(part, out_rp, probsb);
  pack_vt<<<dim3(4, 64, 8), blk, 0, stream>>>(vb, vt);
  gemm_bt<0, 7><<<dim3(2, 48, 8), blk, 0, stream>>>(probsb, vt, nullptr, nullptr, ctx1, 256, 256, 256, 65536LL, 1572864LL, 0, 0, 1.f);
  if (xf32)
    gemm_bt<0, 3><<<dim3(128, 6, 1), blk, 0, stream>>>(ctx1, w_ro, ro_b, x_in, x_cur, 768, 768, 768, 0, 0, 0, 768, 1.f);
  else
    gemm_bt<0, 4><<<dim3(128, 6, 1), blk, 0, stream>>>(ctx1, w_ro, ro_b, x_in, x_cur, 768, 768, 768, 0, 0, 0, 768, 1.f);

  // ---- Stage 2: column attention ----
  if (xf32) ln_kernel<true><<<4096, blk, 0, stream>>>(x_cur, lnc_w, lnc_b, xn);
  else      ln_kernel<false><<<4096, blk, 0, stream>>>(x_cur, lnc_w, lnc_b, xn);
  gemm_bt<0, 8><<<dim3(128, 18, 1), blk, 0, stream>>>(xn, w_cqkv, qkvb_col, nullptr, qb, 768, 768, 768, 0, 0, 0, 768, 1.f);
  col_attn<<<dim3(256, 8), blk, 0, stream>>>(qb, kb, vb, out_cp, ctx2);
  if (xf32)
    gemm_bt<0, 3><<<dim3(128, 6, 1), blk, 0, stream>>>(ctx2, w_co, co_b, x_cur, x_cur, 768, 768, 768, 0, 0, 0, 768, 1.f);
  else
    gemm_bt<0, 6><<<dim3(128, 6, 1), blk, 0, stream>>>(ctx2, w_co, co_b, x_cur, x_cur, 768, 768, 768, 0, 0, 0, 768, 1.f);

  // ---- Stage 3: FFN (F chunked 2x1536 so hidden fits qb+kb) ----
  if (xf32) ln_kernel<true><<<4096, blk, 0, stream>>>(x_cur, lnf_w, lnf_b, xn3);
  else      ln_kernel<false><<<4096, blk, 0, stream>>>(x_cur, lnf_w, lnf_b, xn3);
  // chunk 0
  gemm_bt<0, 2><<<dim3(128, 12, 1), blk, 0, stream>>>(xn3, w_f1, f1_b, nullptr, hidden, 768, 768, 768, 0, 0, 0, 1536, 1.f);
  if (xf32)
    gemm_bt<0, 3><<<dim3(128, 6, 1), blk, 0, stream>>>(hidden, w_f2, f2_b, x_cur, out_x, 1536, 1536, 3072, 0, 0, 0, 768, 1.f);
  else
    gemm_bt<0, 5><<<dim3(128, 6, 1), blk, 0, stream>>>(hidden, w_f2, f2_b, x_cur, out_x, 1536, 1536, 3072, 0, 0, 0, 768, 1.f);
  // chunk 1 (accumulate into out_x)
  gemm_bt<0, 2><<<dim3(128, 12, 1), blk, 0, stream>>>(xn3, w_f1 + 1536 * 768, f1_b + 1536, nullptr, hidden, 768, 768, 768, 0, 0, 0, 1536, 1.f);
  gemm_bt<0, 3><<<dim3(128, 6, 1), blk, 0, stream>>>(hidden, w_f2 + 1536, nullptr, out_x, out_x, 1536, 1536, 3072, 0, 0, 0, 768, 1.f);
}

// Round 8
// 620.089 us; speedup vs baseline: 1.3362x; 1.0654x over previous
//
#include <hip/hip_runtime.h>
#include <cstdint>

typedef unsigned short u16;
typedef __attribute__((ext_vector_type(8))) short short8;   // 8 x bf16 (4 VGPR)
typedef __attribute__((ext_vector_type(4))) short short4v;  // 4 x bf16
typedef __attribute__((ext_vector_type(4))) float floatx4;  // MFMA acc / float4

#define DEV __device__ __forceinline__

DEV float bf2f(u16 u) { union { uint32_t i; float f; } w; w.i = ((uint32_t)u) << 16; return w.f; }
DEV u16 f2bf(float f) {
  union { float f; uint32_t i; } w; w.f = f;
  uint32_t x = w.i;
  return (u16)((x + 0x7fffu + ((x >> 16) & 1u)) >> 16);  // RNE
}

// fast exact-gelu: A&S 7.1.26 erf approx, |err|<=1.5e-7, branchless
DEV float fast_gelu(float x) {
  const float y = x * 0.70710678118f;
  const float ay = fabsf(y);
  const float t = 1.f / (1.f + 0.3275911f * ay);
  const float poly = t * (0.254829592f + t * (-0.284496736f +
                     t * (1.421413741f + t * (-1.453152027f + t * 1.061405429f))));
  const float er = 1.f - poly * __expf(-y * y);
  const float erf_y = __builtin_copysignf(er, y);
  return 0.5f * x * (1.f + erf_y);
}

// async global->LDS, 16B per lane. LDS dest must be wave-uniform base; HW adds lane*16.
DEV void async_copy16(const u16* g, u16* l) {
  __builtin_amdgcn_global_load_lds(
      (const __attribute__((address_space(1))) void*)(uintptr_t)g,
      (__attribute__((address_space(3))) void*)(uint32_t)(uintptr_t)l,
      16, 0, 0);
}

// ---------------- fused f32 -> bf16 weight convert (all 10 weights) ----------------
struct CvtArgs {
  const float* src[10];
  float scale[10];
};
__global__ __launch_bounds__(256) void cvt_all(CvtArgs a, u16* __restrict__ dst) {
  const size_t e = ((size_t)blockIdx.x * 256 + threadIdx.x) * 4;  // 9437184 total elems
  if (e >= 9437184) return;
  int reg;
  size_t base;
  if (e < 4718592) { reg = (int)(e / 589824); base = (size_t)reg * 589824; }
  else if (e < 7077888) { reg = 8; base = 4718592; }
  else { reg = 9; base = 7077888; }
  const float sc = a.scale[reg];
  floatx4 f = *(const floatx4*)(a.src[reg] + (e - base));
  short4v o;
#pragma unroll
  for (int j = 0; j < 4; ++j) o[j] = (short)f2bf(f[j] * sc);
  *(short4v*)(dst + e) = o;
}

// pack q/k/v biases into one [2304] f32 buffer per stage, q part pre-scaled
__global__ __launch_bounds__(256) void bias_pack(const float* __restrict__ qb,
                                                 const float* __restrict__ kb,
                                                 const float* __restrict__ vb,
                                                 float sq, float* __restrict__ out) {
  const int i = blockIdx.x * 256 + threadIdx.x;
  if (i >= 2304) return;
  const int buf = i / 768, c = i - buf * 768;
  out[i] = buf == 0 ? qb[c] * sq : (buf == 1 ? kb[c] : vb[c]);
}

// ---------------- LayerNorm: one wave per row of 768, bf16 out ----------------
template<bool INF32>
__global__ __launch_bounds__(256) void ln_kernel(const void* __restrict__ in,
                                                 const float* __restrict__ w,
                                                 const float* __restrict__ b,
                                                 u16* __restrict__ out) {
  const int wid = threadIdx.x >> 6, lane = threadIdx.x & 63;
  const int row = blockIdx.x * 4 + wid;  // 16384 rows
  const size_t base = (size_t)row * 768;
  float v[12];
#pragma unroll
  for (int p = 0; p < 3; ++p) {
    const int e = p * 256 + lane * 4;
    if constexpr (INF32) {
      floatx4 f = *(const floatx4*)((const float*)in + base + e);
#pragma unroll
      for (int j = 0; j < 4; ++j) v[p * 4 + j] = f[j];
    } else {
      short4v u = *(const short4v*)((const u16*)in + base + e);
#pragma unroll
      for (int j = 0; j < 4; ++j) v[p * 4 + j] = bf2f((u16)u[j]);
    }
  }
  float s = 0.f, sq = 0.f;
#pragma unroll
  for (int i = 0; i < 12; ++i) { s += v[i]; sq += v[i] * v[i]; }
#pragma unroll
  for (int m = 1; m < 64; m <<= 1) { s += __shfl_xor(s, m); sq += __shfl_xor(sq, m); }
  const float mean = s * (1.f / 768.f);
  const float var = sq * (1.f / 768.f) - mean * mean;
  const float rstd = rsqrtf(var + 1e-5f);
#pragma unroll
  for (int p = 0; p < 3; ++p) {
    const int e = p * 256 + lane * 4;
    floatx4 wv = *(const floatx4*)(w + e);
    floatx4 bv = *(const floatx4*)(b + e);
    short4v o;
#pragma unroll
    for (int j = 0; j < 4; ++j) {
      float y = (v[p * 4 + j] - mean) * rstd * wv[j] + bv[j];
      o[j] = (short)f2bf(y);
    }
    *(short4v*)(out + base + e) = o;
  }
}

// ---------------- GEMM: C[M,N] = A[M,K] * B[N,K]^T (+epilogue) ----------------
// 128x128 tile, BK=32, 4 waves (2x2), mfma_f32_16x16x32_bf16.
// NEW: 3-buffer LDS rotation + counted vmcnt(4) (never 0 in main loop) + raw
// s_barrier + setprio around MFMA + 4-way-reducing XOR swizzle (both sides).
// AMODE: 0 = normal strides lda/ldb
//        1 = row-attn logits addressing: elem(row,kk) = base + z*96 + (kk/96)*196608 + row*768 + (kk%96)
//        2 = split-K row-attn logits: z = h*16+s, head h, K-window [s*384, s*384+384)
// EPI: 1 f32=acc | 2 bf16=gelu(acc+bz) | 3 f32=resf32+acc+bz | 4 bf16=resf32+acc+bz
//      5 f32=resbf16+acc+bz | 6 bf16=resbf16+acc+bz
//      7 bf16 scatter (row-attn PV): n=(r*96+d) -> out[(r*256+m)*768 + z*96 + d]
//      8 bf16 merged-QKV split write: buf=n/768 -> out + buf*12582912 + m*768 + (n%768)
template<int AMODE>
DEV void stage_tile(const u16* __restrict__ Ab, const u16* __restrict__ Bb,
                    int m0, int n0, int lda, int ldb, int kk0, int t,
                    u16* ldsA, u16* ldsB) {
  const int wid = t >> 6;
  // swizzled source col: logical col stored at physical (t&3)*8 is ((t&3)^(r&3))*8
  const int col = (((t & 3) ^ ((t >> 2) & 3)) << 3);
#pragma unroll
  for (int i = 0; i < 2; ++i) {
    const int r = i * 64 + (t >> 2);
    const int kk = kk0 + col;
    const u16 *ga, *gb;
    if constexpr (AMODE == 0) {
      ga = Ab + (size_t)(m0 + r) * lda + kk;
      gb = Bb + (size_t)(n0 + r) * ldb + kk;
    } else {
      const int r96 = kk / 96, d = kk - r96 * 96;  // 8|96: chunk never crosses r96
      ga = Ab + (size_t)r96 * 196608 + (size_t)(m0 + r) * 768 + d;
      gb = Bb + (size_t)r96 * 196608 + (size_t)(n0 + r) * 768 + d;
    }
    async_copy16(ga, ldsA + i * 2048 + wid * 512);
    async_copy16(gb, ldsB + i * 2048 + wid * 512);
  }
}

template<int AMODE, int EPI>
__global__ __launch_bounds__(256) void gemm_bt(
    const u16* __restrict__ A, const u16* __restrict__ B,
    const float* __restrict__ bias, const void* __restrict__ res,
    void* __restrict__ out, int K, int lda, int ldb,
    long long aBatch, long long bBatch, long long outBatch, int ldc, float scale) {
  __shared__ u16 lds[3 * 8192];  // 3 x (A 128x32 + B 128x32) = 48KB
  const int t = threadIdx.x;
  const int z = blockIdx.z;
  const int m0 = blockIdx.x * 128, n0 = blockIdx.y * 128;
  const u16* Ab;
  const u16* Bb;
  int koff = 0;
  if constexpr (AMODE == 0) { Ab = A + (size_t)z * aBatch; Bb = B + (size_t)z * bBatch; }
  else if constexpr (AMODE == 1) { Ab = A + z * 96; Bb = B + z * 96; }
  else { const int h = z >> 4; Ab = A + h * 96; Bb = B + h * 96; koff = (z & 15) * 384; }

  const int wid = t >> 6, lane = t & 63;
  const int wr = wid >> 1, wc = wid & 1;
  const int lrow = lane & 15, lhi = lane >> 4;
  const int swl = lrow & 3;  // read-side swizzle key (ra&3 == lrow&3)

  floatx4 acc[4][4];
#pragma unroll
  for (int i = 0; i < 4; ++i)
#pragma unroll
    for (int j = 0; j < 4; ++j) acc[i][j] = (floatx4){0.f, 0.f, 0.f, 0.f};

  const int NT = K >> 5;  // K/32 tiles (all K are multiples of 32)

  // prologue: stage tiles 0 and 1
  stage_tile<AMODE>(Ab, Bb, m0, n0, lda, ldb, koff, t, lds, lds + 4096);
  if (NT > 1)
    stage_tile<AMODE>(Ab, Bb, m0, n0, lda, ldb, koff + 32, t, lds + 8192, lds + 8192 + 4096);
  if (NT > 2) asm volatile("s_waitcnt vmcnt(4)" ::: "memory");
  else        asm volatile("s_waitcnt vmcnt(0)" ::: "memory");
  __builtin_amdgcn_s_barrier();
  asm volatile("" ::: "memory");

  int cur = 0, nxt = 2;
  for (int kt = 0; kt < NT; ++kt) {
    const bool more = (kt + 2) < NT;
    if (more)
      stage_tile<AMODE>(Ab, Bb, m0, n0, lda, ldb, koff + (kt + 2) * 32, t,
                        lds + nxt * 8192, lds + nxt * 8192 + 4096);

    const u16* lA = lds + cur * 8192;
    const u16* lB = lA + 4096;
    short8 af[4], bfr[4];
#pragma unroll
    for (int mi = 0; mi < 4; ++mi)
      af[mi] = *(const short8*)&lA[(wr * 64 + mi * 16 + lrow) * 32 + ((lhi ^ swl) << 3)];
#pragma unroll
    for (int ni = 0; ni < 4; ++ni)
      bfr[ni] = *(const short8*)&lB[(wc * 64 + ni * 16 + lrow) * 32 + ((lhi ^ swl) << 3)];

    __builtin_amdgcn_s_setprio(1);
#pragma unroll
    for (int mi = 0; mi < 4; ++mi)
#pragma unroll
      for (int ni = 0; ni < 4; ++ni)
        acc[mi][ni] = __builtin_amdgcn_mfma_f32_16x16x32_bf16(af[mi], bfr[ni], acc[mi][ni], 0, 0, 0);
    __builtin_amdgcn_s_setprio(0);

    if (kt + 1 < NT) {
      if (more) asm volatile("s_waitcnt vmcnt(4)" ::: "memory");  // kt+1 landed, kt+2 in flight
      else      asm volatile("s_waitcnt vmcnt(0)" ::: "memory");  // tail drain
      __builtin_amdgcn_s_barrier();
      asm volatile("" ::: "memory");
    }
    cur = (cur == 2) ? 0 : cur + 1;
    nxt = (nxt == 2) ? 0 : nxt + 1;
  }

  const int mbase = m0 + wr * 64;
  const int nbase = n0 + wc * 64;
#pragma unroll
  for (int mi = 0; mi < 4; ++mi) {
#pragma unroll
    for (int ni = 0; ni < 4; ++ni) {
      const int n = nbase + ni * 16 + lrow;
      float bz = 0.f;
      if constexpr (EPI != 1 && EPI != 7) { if (bias) bz = bias[n]; }
#pragma unroll
      for (int r4 = 0; r4 < 4; ++r4) {
        const int m = mbase + mi * 16 + lhi * 4 + r4;
        const float val = acc[mi][ni][r4];
        if constexpr (EPI == 1) {
          ((float*)out)[(size_t)z * outBatch + (size_t)m * ldc + n] = val;
        } else if constexpr (EPI == 2) {
          ((u16*)out)[(size_t)m * ldc + n] = f2bf(fast_gelu(val + bz));
        } else if constexpr (EPI == 3) {
          const float r = ((const float*)res)[(size_t)m * ldc + n];
          ((float*)out)[(size_t)m * ldc + n] = r + val + bz;
        } else if constexpr (EPI == 4) {
          const float r = ((const float*)res)[(size_t)m * ldc + n];
          ((u16*)out)[(size_t)m * ldc + n] = f2bf(r + val + bz);
        } else if constexpr (EPI == 5) {
          const float r = bf2f(((const u16*)res)[(size_t)m * ldc + n]);
          ((float*)out)[(size_t)m * ldc + n] = r + val + bz;
        } else if constexpr (EPI == 6) {
          const float r = bf2f(((const u16*)res)[(size_t)m * ldc + n]);
          ((u16*)out)[(size_t)m * ldc + n] = f2bf(r + val + bz);
        } else if constexpr (EPI == 7) {
          const int rr = n / 96, d = n - rr * 96;
          ((u16*)out)[((size_t)(rr * 256 + m)) * 768 + (size_t)z * 96 + d] = f2bf(val);
        } else if constexpr (EPI == 8) {
          const int buf = n / 768, col = n - buf * 768;
          ((u16*)out)[(size_t)buf * 12582912 + (size_t)m * 768 + col] = f2bf(val + bz);
        }
      }
    }
  }
}

// ---------------- row softmax fused with split-K reduce ----------------
__global__ __launch_bounds__(256) void softmax_row(const float* __restrict__ part,
                                                   float* __restrict__ probs_f,
                                                   u16* __restrict__ probs_b) {
  const int wid = threadIdx.x >> 6, lane = threadIdx.x & 63;
  const int row = blockIdx.x * 4 + wid;
  const int h = row >> 8, i = row & 255;
  const size_t base = (size_t)h * 16 * 65536 + (size_t)i * 256 + lane * 4;
  floatx4 v = (floatx4){0.f, 0.f, 0.f, 0.f};
#pragma unroll
  for (int s16 = 0; s16 < 16; ++s16) {
    floatx4 p = *(const floatx4*)(part + base + (size_t)s16 * 65536);
#pragma unroll
    for (int j = 0; j < 4; ++j) v[j] += p[j];
  }
  float mx = fmaxf(fmaxf(v[0], v[1]), fmaxf(v[2], v[3]));
#pragma unroll
  for (int m = 1; m < 64; m <<= 1) mx = fmaxf(mx, __shfl_xor(mx, m));
  float e[4], s = 0.f;
#pragma unroll
  for (int j = 0; j < 4; ++j) { e[j] = __expf(v[j] - mx); s += e[j]; }
#pragma unroll
  for (int m = 1; m < 64; m <<= 1) s += __shfl_xor(s, m);
  const float inv = 1.f / s;
  floatx4 of;
  short4v ob;
#pragma unroll
  for (int j = 0; j < 4; ++j) {
    const float p = e[j] * inv;
    of[j] = p;
    ob[j] = (short)f2bf(p);
  }
  *(floatx4*)(probs_f + (size_t)row * 256 + lane * 4) = of;
  *(short4v*)(probs_b + (size_t)row * 256 + lane * 4) = ob;
}

// ---------------- pack V^T for row-attn PV: vt[h][(r*96+d)][j] = v[(r*256+j)*768+h*96+d]
__global__ __launch_bounds__(256) void pack_vt(const u16* __restrict__ v, u16* __restrict__ vt) {
  __shared__ u16 S[64][104];  // [j][d], padded
  const int jb = blockIdx.x, r = blockIdx.y, h = blockIdx.z;
  const int t = threadIdx.x;
#pragma unroll
  for (int p = 0; p < 3; ++p) {
    const int cid = t + p * 256;
    const int j = cid / 12, ch = cid - j * 12;
    short8 x = *(const short8*)&v[((size_t)(r * 256 + jb * 64 + j)) * 768 + h * 96 + ch * 8];
    *(short8*)&S[j][ch * 8] = x;
  }
  __syncthreads();
#pragma unroll
  for (int p = 0; p < 3; ++p) {
    const int cid = t + p * 256;
    const int d = cid / 8, cj = cid - d * 8;
    u16 tmp[8];
#pragma unroll
    for (int m = 0; m < 8; ++m) tmp[m] = S[cj * 8 + m][d];
    *(short8*)&vt[((size_t)(h * 6144 + r * 96 + d)) * 256 + jb * 64 + cj * 8] = *(short8*)tmp;
  }
}

// ---------------- fused column attention: one block per (c, h) ----------------
__global__ __launch_bounds__(256) void col_attn(const u16* __restrict__ q,
                                                const u16* __restrict__ k,
                                                const u16* __restrict__ v,
                                                float* __restrict__ probs,
                                                u16* __restrict__ ctx) {
  __shared__ u16 qs[64][104];
  __shared__ u16 ks[64][104];
  __shared__ u16 vt[96][72];
  __shared__ u16 ps[64][72];
  const int c = blockIdx.x, h = blockIdx.y;
  const int t = threadIdx.x;
#pragma unroll
  for (int p = 0; p < 3; ++p) {
    const int cid = t + p * 256;
    const int i = cid / 12, ch = cid - i * 12;
    const size_t g = ((size_t)(i * 256 + c)) * 768 + h * 96 + ch * 8;
    short8 qv = *(const short8*)(q + g);
    short8 kv = *(const short8*)(k + g);
    short8 vv = *(const short8*)(v + g);
    *(short8*)&qs[i][ch * 8] = qv;
    *(short8*)&ks[i][ch * 8] = kv;
#pragma unroll
    for (int m = 0; m < 8; ++m) vt[ch * 8 + m][i] = (u16)vv[m];
  }
  __syncthreads();
  const int lane = t & 63, wid = t >> 6;
  const int lrow = lane & 15, lhi = lane >> 4;

  floatx4 s[4];
#pragma unroll
  for (int nj = 0; nj < 4; ++nj) s[nj] = (floatx4){0.f, 0.f, 0.f, 0.f};
#pragma unroll
  for (int kk = 0; kk < 3; ++kk) {
    short8 a = *(const short8*)&qs[wid * 16 + lrow][kk * 32 + lhi * 8];
#pragma unroll
    for (int nj = 0; nj < 4; ++nj) {
      short8 bb = *(const short8*)&ks[nj * 16 + lrow][kk * 32 + lhi * 8];
      s[nj] = __builtin_amdgcn_mfma_f32_16x16x32_bf16(a, bb, s[nj], 0, 0, 0);
    }
  }
  const size_t pb = ((size_t)(h * 256 + c)) * 4096;
#pragma unroll
  for (int r4 = 0; r4 < 4; ++r4) {
    float mx = fmaxf(fmaxf(s[0][r4], s[1][r4]), fmaxf(s[2][r4], s[3][r4]));
    mx = fmaxf(mx, __shfl_xor(mx, 1));
    mx = fmaxf(mx, __shfl_xor(mx, 2));
    mx = fmaxf(mx, __shfl_xor(mx, 4));
    mx = fmaxf(mx, __shfl_xor(mx, 8));
    float e[4], sum = 0.f;
#pragma unroll
    for (int nj = 0; nj < 4; ++nj) { e[nj] = __expf(s[nj][r4] - mx); sum += e[nj]; }
    sum += __shfl_xor(sum, 1);
    sum += __shfl_xor(sum, 2);
    sum += __shfl_xor(sum, 4);
    sum += __shfl_xor(sum, 8);
    const float inv = 1.f / sum;
    const int i = wid * 16 + lhi * 4 + r4;
#pragma unroll
    for (int nj = 0; nj < 4; ++nj) {
      const float pv = e[nj] * inv;
      const int j = nj * 16 + lrow;
      probs[pb + (size_t)i * 64 + j] = pv;
      ps[i][j] = f2bf(pv);
    }
  }
  __syncthreads();
  floatx4 o[6];
#pragma unroll
  for (int df = 0; df < 6; ++df) o[df] = (floatx4){0.f, 0.f, 0.f, 0.f};
#pragma unroll
  for (int k2 = 0; k2 < 2; ++k2) {
    short8 a = *(const short8*)&ps[wid * 16 + lrow][k2 * 32 + lhi * 8];
#pragma unroll
    for (int df = 0; df < 6; ++df) {
      short8 bb = *(const short8*)&vt[df * 16 + lrow][k2 * 32 + lhi * 8];
      o[df] = __builtin_amdgcn_mfma_f32_16x16x32_bf16(a, bb, o[df], 0, 0, 0);
    }
  }
#pragma unroll
  for (int df = 0; df < 6; ++df)
#pragma unroll
    for (int r4 = 0; r4 < 4; ++r4) {
      const int i = wid * 16 + lhi * 4 + r4;
      const int d = df * 16 + lrow;
      ctx[((size_t)(i * 256 + c)) * 768 + h * 96 + d] = f2bf(o[df][r4]);
    }
}

// ---------------- host launch ----------------
extern "C" void kernel_launch(void* const* d_in, const int* in_sizes, int n_in,
                              void* d_out, int out_size, void* d_ws, size_t ws_size,
                              hipStream_t stream) {
  const float* x_in  = (const float*)d_in[0];
  const float* lnr_w = (const float*)d_in[1];
  const float* lnr_b = (const float*)d_in[2];
  const float* rq_w  = (const float*)d_in[3];
  const float* rq_b  = (const float*)d_in[4];
  const float* rk_w  = (const float*)d_in[5];
  const float* rk_b  = (const float*)d_in[6];
  const float* rv_w  = (const float*)d_in[7];
  const float* rv_b  = (const float*)d_in[8];
  const float* ro_w  = (const float*)d_in[9];
  const float* ro_b  = (const float*)d_in[10];
  const float* lnc_w = (const float*)d_in[11];
  const float* lnc_b = (const float*)d_in[12];
  const float* cq_w  = (const float*)d_in[13];
  const float* cq_b  = (const float*)d_in[14];
  const float* ck_w  = (const float*)d_in[15];
  const float* ck_b  = (const float*)d_in[16];
  const float* cv_w  = (const float*)d_in[17];
  const float* cv_b  = (const float*)d_in[18];
  const float* co_w  = (const float*)d_in[19];
  const float* co_b  = (const float*)d_in[20];
  const float* lnf_w = (const float*)d_in[21];
  const float* lnf_b = (const float*)d_in[22];
  const float* f1_w  = (const float*)d_in[23];
  const float* f1_b  = (const float*)d_in[24];
  const float* f2_w  = (const float*)d_in[25];
  const float* f2_b  = (const float*)d_in[26];

  const float s_row = 0.0127577591f;  // (96^-0.5)/8
  const float s_col = 0.1020620726f;  // 96^-0.5

  // ---- ws layout ----
  char* ws = (char*)d_ws;
  const size_t WSZ_E = 589824 * 2;        // one E x E bf16 weight
  u16* w_all = (u16*)ws;                  // rq,rk,rv | ro | cq,ck,cv | co | f1 | f2
  u16* w_rqkv = w_all;
  u16* w_ro   = (u16*)(ws + 3 * WSZ_E);
  u16* w_cqkv = (u16*)(ws + 4 * WSZ_E);
  u16* w_co   = (u16*)(ws + 7 * WSZ_E);
  u16* w_f1   = (u16*)(ws + 8 * WSZ_E);                 // 4,718,592 B
  u16* w_f2   = (u16*)(ws + 8 * WSZ_E + 4718592);       // 4,718,592 B
  size_t off = 8 * WSZ_E + 2 * 4718592;                 // 18,874,368

  const bool xf32 = ws_size >= 147849216ULL;            // f32 residual if it fits
  char* x_cur = ws + off;                               // f32 (50.3MB) or bf16 (25.2MB)
  off += xf32 ? 50331648 : 25165824;
  u16* qb = (u16*)(ws + off); off += 25165824;
  u16* kb = (u16*)(ws + off); off += 25165824;
  u16* vb = (u16*)(ws + off); off += 25165824;
  u16* probsb = (u16*)(ws + off); off += 1048576;       // bf16 row probs
  float* qkvb_row = (float*)(ws + off); off += 9216;    // [2304] f32
  float* qkvb_col = (float*)(ws + off); off += 9216;

  u16* vt     = qb;            // row-attn V^T overlays qb (free after logits)
  u16* ctx1   = kb;            // row-attn context overlays kb
  u16* hidden = qb;            // FFN hidden chunk (50.3MB) overlays qb+kb
  u16* xn3    = vb;            // stage-3 LN output overlays vb

  // ---- d_out layout + d_out-as-scratch ----
  float* out_x  = (float*)d_out;            // 12,582,912 f32 (free until final fc2)
  float* out_rp = out_x + 12582912;         // row_probs [8,1,256,256] f32
  float* out_cp = out_x + 13107200;         // col_probs [8,256,1,64,64] f32
  u16* xn   = (u16*)out_x;                  // LN out (stages 1,2), lower half of out_x
  u16* ctx2 = (u16*)((char*)out_x + 25165824);  // col-attn context, upper half
  float* part = out_x;                      // split-K logits partials (33.5MB, dead after softmax)

  const dim3 blk(256);

  // ---- weight conversion (one dispatch) + bias packs ----
  CvtArgs ca;
  ca.src[0] = rq_w; ca.src[1] = rk_w; ca.src[2] = rv_w; ca.src[3] = ro_w;
  ca.src[4] = cq_w; ca.src[5] = ck_w; ca.src[6] = cv_w; ca.src[7] = co_w;
  ca.src[8] = f1_w; ca.src[9] = f2_w;
  for (int i = 0; i < 10; ++i) ca.scale[i] = 1.f;
  ca.scale[0] = s_row; ca.scale[4] = s_col;
  cvt_all<<<9216, blk, 0, stream>>>(ca, w_all);
  bias_pack<<<9, blk, 0, stream>>>(rq_b, rk_b, rv_b, s_row, qkvb_row);
  bias_pack<<<9, blk, 0, stream>>>(cq_b, ck_b, cv_b, s_col, qkvb_col);

  // ---- Stage 1: row attention ----
  ln_kernel<true><<<4096, blk, 0, stream>>>(x_in, lnr_w, lnr_b, xn);
  gemm_bt<0, 8><<<dim3(128, 18, 1), blk, 0, stream>>>(xn, w_rqkv, qkvb_row, nullptr, qb, 768, 768, 768, 0, 0, 0, 768, 1.f);
  // split-K logits: grid.z = h*16+s, partials into d_out scratch (xn is dead now)
  gemm_bt<2, 1><<<dim3(2, 2, 128), blk, 0, stream>>>(qb, kb, nullptr, nullptr, part, 384, 0, 0, 0, 0, 65536LL, 256, 1.f);
  softmax_row<<<512, blk, 0, stream>>>(part, out_rp, probsb);
  pack_vt<<<dim3(4, 64, 8), blk, 0, stream>>>(vb, vt);
  gemm_bt<0, 7><<<dim3(2, 48, 8), blk, 0, stream>>>(probsb, vt, nullptr, nullptr, ctx1, 256, 256, 256, 65536LL, 1572864LL, 0, 0, 1.f);
  if (xf32)
    gemm_bt<0, 3><<<dim3(128, 6, 1), blk, 0, stream>>>(ctx1, w_ro, ro_b, x_in, x_cur, 768, 768, 768, 0, 0, 0, 768, 1.f);
  else
    gemm_bt<0, 4><<<dim3(128, 6, 1), blk, 0, stream>>>(ctx1, w_ro, ro_b, x_in, x_cur, 768, 768, 768, 0, 0, 0, 768, 1.f);

  // ---- Stage 2: column attention ----
  if (xf32) ln_kernel<true><<<4096, blk, 0, stream>>>(x_cur, lnc_w, lnc_b, xn);
  else      ln_kernel<false><<<4096, blk, 0, stream>>>(x_cur, lnc_w, lnc_b, xn);
  gemm_bt<0, 8><<<dim3(128, 18, 1), blk, 0, stream>>>(xn, w_cqkv, qkvb_col, nullptr, qb, 768, 768, 768, 0, 0, 0, 768, 1.f);
  col_attn<<<dim3(256, 8), blk, 0, stream>>>(qb, kb, vb, out_cp, ctx2);
  if (xf32)
    gemm_bt<0, 3><<<dim3(128, 6, 1), blk, 0, stream>>>(ctx2, w_co, co_b, x_cur, x_cur, 768, 768, 768, 0, 0, 0, 768, 1.f);
  else
    gemm_bt<0, 6><<<dim3(128, 6, 1), blk, 0, stream>>>(ctx2, w_co, co_b, x_cur, x_cur, 768, 768, 768, 0, 0, 0, 768, 1.f);

  // ---- Stage 3: FFN (F chunked 2x1536 so hidden fits qb+kb) ----
  if (xf32) ln_kernel<true><<<4096, blk, 0, stream>>>(x_cur, lnf_w, lnf_b, xn3);
  else      ln_kernel<false><<<4096, blk, 0, stream>>>(x_cur, lnf_w, lnf_b, xn3);
  // chunk 0
  gemm_bt<0, 2><<<dim3(128, 12, 1), blk, 0, stream>>>(xn3, w_f1, f1_b, nullptr, hidden, 768, 768, 768, 0, 0, 0, 1536, 1.f);
  if (xf32)
    gemm_bt<0, 3><<<dim3(128, 6, 1), blk, 0, stream>>>(hidden, w_f2, f2_b, x_cur, out_x, 1536, 1536, 3072, 0, 0, 0, 768, 1.f);
  else
    gemm_bt<0, 5><<<dim3(128, 6, 1), blk, 0, stream>>>(hidden, w_f2, f2_b, x_cur, out_x, 1536, 1536, 3072, 0, 0, 0, 768, 1.f);
  // chunk 1 (accumulate into out_x)
  gemm_bt<0, 2><<<dim3(128, 12, 1), blk, 0, stream>>>(xn3, w_f1 + 1536 * 768, f1_b + 1536, nullptr, hidden, 768, 768, 768, 0, 0, 0, 1536, 1.f);
  gemm_bt<0, 3><<<dim3(128, 6, 1), blk, 0, stream>>>(hidden, w_f2 + 1536, nullptr, out_x, out_x, 1536, 1536, 3072, 0, 0, 0, 768, 1.f);
}